// Round 12
// baseline (153.422 us; speedup 1.0000x reference)
//
#include <hip/hip_runtime.h>

typedef _Float16 f16_t;
typedef f16_t f16x8 __attribute__((ext_vector_type(8)));
typedef f16_t f16x4 __attribute__((ext_vector_type(4)));
typedef float f32x4 __attribute__((ext_vector_type(4)));

#define MFMA16(a,b,c) __builtin_amdgcn_mfma_f32_16x16x32_f16(a,b,c,0,0,0)
#define VM0 asm volatile("s_waitcnt vmcnt(0)" ::: "memory")
#define VM2 asm volatile("s_waitcnt vmcnt(2)" ::: "memory")

// async global -> LDS, 16B per lane (dest = wave-uniform base + lane*16).
__device__ __forceinline__ void cp16(const void* g, void* l){
  __builtin_amdgcn_global_load_lds(
      (const __attribute__((address_space(1))) void*)g,
      (__attribute__((address_space(3))) void*)l, 16, 0, 0);
}

__device__ __forceinline__ f16x8 cvt8h(float4 a, float4 b){
  f16x8 r;
  r[0]=(f16_t)a.x; r[1]=(f16_t)a.y; r[2]=(f16_t)a.z; r[3]=(f16_t)a.w;
  r[4]=(f16_t)b.x; r[5]=(f16_t)b.y; r[6]=(f16_t)b.z; r[7]=(f16_t)b.w;
  return r;
}

// Stage rows x 256 f32 (row-major) -> LDS f16 [row][256], per-row XOR swizzle
// on 16B chunks: chunk' = chunk ^ (row&7). Row pitch 512B.
template<int NT>
__device__ __forceinline__ void stage_f16(const float* __restrict__ src,
                                          char* dst, int rows, int tid){
  const int nchunk = rows * 32;
  const float4* s4 = reinterpret_cast<const float4*>(src);
  for (int cid = tid; cid < nchunk; cid += NT){
    int r = cid >> 5, c = cid & 31;
    *reinterpret_cast<f16x8*>(dst + r*512 + ((c ^ (r&7))<<4)) = cvt8h(s4[cid*2], s4[cid*2+1]);
  }
}

__device__ __forceinline__ f16x8 ldsA(const char* buf, int row, int c16){
  return *reinterpret_cast<const f16x8*>(buf + row*512 + ((c16 ^ (row&7))<<4));
}

// ---- wave-private W pipeline (bank-conflict-free source permutation) ------
// Lane l loads W[(n0 + (l&15))*256 + kb*32 + (l>>4)*8] into linear LDS slot
// l*16. B-fragment read for lane (lo16,hi4) = addr lane*16 (conflict-free);
// global side: 4 lanes {l, l+16, l+32, l+48} cover one row's 64B segment.
__device__ __forceinline__ void issue_tile(const f16_t* wsrc_lane, int kb, char* wt, int lane){
  const f16_t* s = wsrc_lane + kb*32;
  char* d = wt + (kb&1)*2048 + lane*16;
  cp16(s, d);
  cp16(s + 16*256, d + 1024);
}

// 64x32 C tile, K=256, software-pipelined: consume tile kb (vmcnt(2): tile
// kb+1 stays in flight), then issue tile kb+2 into the slot kb just freed.
// T5: setprio(1) around the MFMA cluster (2 blocks/CU at different phases).
__device__ __forceinline__ void gemm_pipe(f32x4 acc[4][2], const char* bufA,
    const f16_t* wsrc_lane, char* wt, int lane, int lo16, int hi4){
  #pragma unroll
  for (int kb = 0; kb < 8; ++kb){
    if (kb < 7) { VM2; } else { VM0; }
    const char* ws = wt + (kb&1)*2048 + lane*16;
    f16x8 bf0 = *reinterpret_cast<const f16x8*>(ws);
    f16x8 bf1 = *reinterpret_cast<const f16x8*>(ws + 1024);
    __builtin_amdgcn_s_setprio(1);
    #pragma unroll
    for (int mb = 0; mb < 4; ++mb){
      f16x8 af = ldsA(bufA, mb*16 + lo16, kb*4 + hi4);
      acc[mb][0] = MFMA16(af, bf0, acc[mb][0]);
      acc[mb][1] = MFMA16(af, bf1, acc[mb][1]);
    }
    __builtin_amdgcn_s_setprio(0);
    __builtin_amdgcn_sched_barrier(0);   // keep the refill below the reads above
    if (kb + 2 < 8) issue_tile(wsrc_lane, kb + 2, wt, lane);
  }
}

// f32-W streaming fallback (only used when ws_size can't hold f16 weights)
__device__ __forceinline__ void gemm_w32(f32x4 acc[4][2], const char* bufA,
    const float* __restrict__ W, int n0, int lo16, int hi4){
  #pragma unroll
  for (int kb = 0; kb < 8; ++kb){
    f16x8 bf[2];
    #pragma unroll
    for (int nb = 0; nb < 2; ++nb){
      const float4* p = reinterpret_cast<const float4*>(W + ((n0 + nb*16 + lo16)<<8) + kb*32 + hi4*8);
      bf[nb] = cvt8h(p[0], p[1]);
    }
    #pragma unroll
    for (int mb = 0; mb < 4; ++mb){
      f16x8 af = ldsA(bufA, mb*16 + lo16, kb*4 + hi4);
      acc[mb][0] = MFMA16(af, bf[0], acc[mb][0]);
      acc[mb][1] = MFMA16(af, bf[1], acc[mb][1]);
    }
  }
}

// ---------------------------------------------------------------------------
// k0_cvt: one-shot f32 -> f16 conversion of W1, W2 into d_ws (Wk no longer
// needed -- GEMM3 was eliminated algebraically).
// ---------------------------------------------------------------------------
__global__ __launch_bounds__(256)
void k0_cvt(const float* __restrict__ W1, const float* __restrict__ W2,
            f16_t* __restrict__ w1h, f16_t* __restrict__ w2h)
{
  const long long NG1 = 2097152, NGT = 4194304; // 8-elem groups
  for (long long gidx = (long long)blockIdx.x*256 + threadIdx.x; gidx < NGT;
       gidx += (long long)gridDim.x*256){
    const float4* s; f16_t* d; long long off;
    if (gidx < NG1){ s = (const float4*)W1; d = w1h; off = gidx; }
    else { s = (const float4*)W2; d = w2h; off = gidx - NG1; }
    *reinterpret_cast<f16x8*>(d + off*8) = cvt8h(s[off*2], s[off*2+1]);
  }
}

// ---------------------------------------------------------------------------
// kqwk: qWkT[b][h][n] = sum_d q[b, n*64+d] * Wk[n*64+d, h]   (f16x4 per (b,h))
//       qbk[b][n]     = sum_d q[b, n*64+d] * bk[n*64+d]
// Folds q and Wk so k2's GEMM3 becomes a per-element 4-FMA dot:
//   scores[b,n,e] = sum_h eo[b,e,h]*qWkT[b,h,n] + qbk[b,n]
// ---------------------------------------------------------------------------
__global__ __launch_bounds__(256)
void kqwk(const float* __restrict__ q, const float* __restrict__ Wk,
          const float* __restrict__ ipb, f16_t* __restrict__ qWkT,
          float* __restrict__ qbk)
{
  __shared__ float qrow[256];
  const int b = blockIdx.x, t = threadIdx.x;
  qrow[t] = q[b*256 + t];
  __syncthreads();
  float s0=0.f, s1=0.f, s2=0.f, s3=0.f;
  #pragma unroll 8
  for (int d = 0; d < 64; ++d){
    s0 += qrow[d]       * Wk[ d       *256 + t];
    s1 += qrow[64 + d]  * Wk[(64 + d) *256 + t];
    s2 += qrow[128 + d] * Wk[(128 + d)*256 + t];
    s3 += qrow[192 + d] * Wk[(192 + d)*256 + t];
  }
  f16x4 o; o[0]=(f16_t)s0; o[1]=(f16_t)s1; o[2]=(f16_t)s2; o[3]=(f16_t)s3;
  *reinterpret_cast<f16x4*>(qWkT + (b*256 + t)*4) = o;
  if (t < 4){
    float sb = 0.f;
    #pragma unroll 8
    for (int d = 0; d < 64; ++d) sb += qrow[t*64 + d] * ipb[256 + t*64 + d];
    qbk[b*4 + t] = sb;
  }
}

// ---------------------------------------------------------------------------
// k2_fused: per (expert e, 64-row batch tile):
//   h = x@W1[e]^T + b1 ; LN ; relu -> hr(f16 LDS) ; eo = hr@W2[e]^T + b2 ->
//   global f32 ; scores partials via qWkT dot (GEMM3 eliminated).
// grid 1024 XCD-swizzled (xcd=l&7 -> e=xcd*32+(l>>5), btile=(l>>3)&3);
// block 512 = 8 col-waves. LDS 74.2KB -> 2 blocks/CU.
// ---------------------------------------------------------------------------
template<int W16>
__global__ __launch_bounds__(512, 4)
void k2_fused(const float* __restrict__ x, const void* __restrict__ W1v,
              const float* __restrict__ b1, const float* __restrict__ g1,
              const float* __restrict__ bb1, const void* __restrict__ W2v,
              const float* __restrict__ b2, const f16_t* __restrict__ qWkT,
              const float* __restrict__ qbk,
              float* __restrict__ eo_out, float* __restrict__ scores)
{
  __shared__ __align__(16) char lds[74240];
  char* bufA = lds;                    // 32KB: x(f16) -> hr(f16)
  float* red = (float*)(lds + 32768);  // 8KB: LN [64][16] / scores [64][8][4]
  float* st  = (float*)(lds + 40960);  // [64][2] = 512B
  char* wpipe = lds + 41472;           // 8 waves x 2 slots x 2KB = 32KB

  const int l = blockIdx.x;
  const int e    = (l & 7) * 32 + (l >> 5);
  const int b0   = ((l >> 3) & 3) * 64;
  const int tid = threadIdx.x;
  const int lane = tid & 63, wid = tid >> 6;
  const int lo16 = lane & 15, hi4 = lane >> 4;
  const int n0 = wid * 32;
  char* wt = wpipe + wid*4096;

  // bank-conflict-free per-lane source permutation (see issue_tile comment)
  const int pl = (n0 + (lane & 15))*256 + (lane >> 4)*8;
  const f16_t* src1 = nullptr; const f16_t* src2 = nullptr;
  if (W16){
    src1 = (const f16_t*)W1v + e*65536 + pl;
    src2 = (const f16_t*)W2v + e*65536 + pl;
    issue_tile(src1, 0, wt, lane);       // G1 prefetch hides under x-stage
    issue_tile(src1, 1, wt, lane);
  }

  stage_f16<512>(x + b0*256, bufA, 64, tid);
  __syncthreads();

  f32x4 acc[4][2];
  #pragma unroll
  for (int mb=0;mb<4;++mb){
    #pragma unroll
    for (int nb=0;nb<2;++nb) acc[mb][nb] = (f32x4)0.0f;
  }

  if (W16) gemm_pipe(acc, bufA, src1, wt, lane, lo16, hi4);
  else     gemm_w32(acc, bufA, (const float*)W1v + e*65536, n0, lo16, hi4);

  if (W16){                              // G2 prefetch hides under LN phase
    issue_tile(src2, 0, wt, lane);
    issue_tile(src2, 1, wt, lane);
  }

  float b1v[2], g1v[2], bbv[2], b2v[2];
  #pragma unroll
  for (int nb=0;nb<2;++nb){
    int c = n0 + nb*16 + lo16;
    b1v[nb] = b1[e*256 + c];
    g1v[nb] = g1[e*256 + c];
    bbv[nb] = bb1[e*256 + c];
    b2v[nb] = b2[e*256 + c];
  }
  #pragma unroll
  for (int mb=0;mb<4;++mb){
    #pragma unroll
    for (int nb=0;nb<2;++nb){
      #pragma unroll
      for (int r=0;r<4;++r) acc[mb][nb][r] += b1v[nb];
    }
  }

  // LN stats: per-row sum/sumsq across the 8 column-waves
  #pragma unroll
  for (int mb=0;mb<4;++mb){
    #pragma unroll
    for (int r=0;r<4;++r){
      float s=0.f, ss=0.f;
      #pragma unroll
      for (int nb=0;nb<2;++nb){ float v = acc[mb][nb][r]; s += v; ss += v*v; }
      #pragma unroll
      for (int m=1;m<16;m<<=1){ s += __shfl_xor(s, m, 64); ss += __shfl_xor(ss, m, 64); }
      if (lo16 == 0){
        int row = mb*16 + hi4*4 + r;
        red[row*16 + wid]     = s;
        red[row*16 + 8 + wid] = ss;
      }
    }
  }
  __syncthreads();   // also: all waves done reading x from bufA
  if (tid < 64){
    float s  = 0.f, ss = 0.f;
    #pragma unroll
    for (int i=0;i<8;++i){ s += red[tid*16 + i]; ss += red[tid*16 + 8 + i]; }
    float mu = s * (1.f/256.f);
    float var = ss * (1.f/256.f) - mu*mu;
    st[tid*2]   = mu;
    st[tid*2+1] = rsqrtf(var + 1e-5f);
  }
  __syncthreads();

  // LN + relu -> hr (f16) back into bufA
  #pragma unroll
  for (int mb=0;mb<4;++mb){
    #pragma unroll
    for (int r=0;r<4;++r){
      int row = mb*16 + hi4*4 + r;
      float mu = st[row*2], rs = st[row*2+1];
      #pragma unroll
      for (int nb=0;nb<2;++nb){
        int c = n0 + nb*16 + lo16;
        float v = (acc[mb][nb][r] - mu) * rs * g1v[nb] + bbv[nb];
        v = fmaxf(v, 0.f);
        int off = row*512 + (((c>>3) ^ (row&7))<<4) + (c&7)*2;
        *reinterpret_cast<f16_t*>(bufA + off) = (f16_t)v;
      }
    }
  }
  __syncthreads();

  // GEMM2: eo = hr @ W2[e]^T + b2
  #pragma unroll
  for (int mb=0;mb<4;++mb){
    #pragma unroll
    for (int nb=0;nb<2;++nb) acc[mb][nb] = (f32x4)0.0f;
  }
  if (W16) gemm_pipe(acc, bufA, src2, wt, lane, lo16, hi4);
  else     gemm_w32(acc, bufA, (const float*)W2v + e*65536, n0, lo16, hi4);

  // epilogue: eo store + scores partials (no bufA write, no barrier needed)
  #pragma unroll
  for (int mb=0;mb<4;++mb){
    #pragma unroll
    for (int r=0;r<4;++r){
      int row = mb*16 + hi4*4 + r;
      int b = b0 + row;
      float p0=0.f, p1=0.f, p2=0.f, p3=0.f;
      #pragma unroll
      for (int nb=0;nb<2;++nb){
        int c = n0 + nb*16 + lo16;
        float v = acc[mb][nb][r] + b2v[nb];
        eo_out[(b*256 + e)*256 + c] = v;
        f16x4 qk = *reinterpret_cast<const f16x4*>(qWkT + (b*256 + c)*4);
        p0 += v * (float)qk[0];
        p1 += v * (float)qk[1];
        p2 += v * (float)qk[2];
        p3 += v * (float)qk[3];
      }
      #pragma unroll
      for (int m=1;m<16;m<<=1){
        p0 += __shfl_xor(p0, m, 64); p1 += __shfl_xor(p1, m, 64);
        p2 += __shfl_xor(p2, m, 64); p3 += __shfl_xor(p3, m, 64);
      }
      if (lo16 == 0){
        red[row*32 + wid*4 + 0] = p0;
        red[row*32 + wid*4 + 1] = p1;
        red[row*32 + wid*4 + 2] = p2;
        red[row*32 + wid*4 + 3] = p3;
      }
    }
  }
  __syncthreads();
  if (tid < 256){
    int row = tid >> 2, n = tid & 3;
    float sc = 0.f;
    #pragma unroll
    for (int w=0;w<8;++w) sc += red[row*32 + w*4 + n];
    scores[((b0 + row)*4 + n)*256 + e] = sc + qbk[(b0 + row)*4 + n];
  }
}

// ---------------------------------------------------------------------------
// k_mini: out = act( maybeLN( (A @ W^T + bias) * scale ) ), 256x256x256, f16.
// grid 8 (32-row tiles), block 512 = 8 col-waves, acc[2][2].
// ---------------------------------------------------------------------------
__global__ __launch_bounds__(512, 4)
void k_mini(const float* __restrict__ A, const float* __restrict__ W,
            const float* __restrict__ bias, float scale, int do_ln,
            const float* __restrict__ g, const float* __restrict__ bb,
            int do_relu, float* __restrict__ out)
{
  __shared__ __align__(16) char lds[18688];
  char* bufA = lds;                    // 16KB: A rows (f16)
  float* red = (float*)(lds + 16384);  // [32][16] = 2KB
  float* st  = (float*)(lds + 18432);  // [32][2]  = 256B

  const int b0 = blockIdx.x * 32;
  const int tid = threadIdx.x;
  const int lane = tid & 63, wid = tid >> 6;
  const int lo16 = lane & 15, hi4 = lane >> 4;
  const int n0 = wid * 32;

  stage_f16<512>(A + b0*256, bufA, 32, tid);
  __syncthreads();

  f32x4 acc[2][2];
  #pragma unroll
  for (int mb=0;mb<2;++mb){
    #pragma unroll
    for (int nb=0;nb<2;++nb) acc[mb][nb] = (f32x4)0.0f;
  }
  #pragma unroll
  for (int kb = 0; kb < 8; ++kb){
    f16x8 bf[2];
    #pragma unroll
    for (int nb = 0; nb < 2; ++nb){
      const float4* p = reinterpret_cast<const float4*>(W + ((n0 + nb*16 + lo16)<<8) + kb*32 + hi4*8);
      bf[nb] = cvt8h(p[0], p[1]);
    }
    #pragma unroll
    for (int mb = 0; mb < 2; ++mb){
      f16x8 af = ldsA(bufA, mb*16 + lo16, kb*4 + hi4);
      acc[mb][0] = MFMA16(af, bf[0], acc[mb][0]);
      acc[mb][1] = MFMA16(af, bf[1], acc[mb][1]);
    }
  }

  float bv[2], gv[2], bbv[2];
  #pragma unroll
  for (int nb=0;nb<2;++nb){
    int c = n0 + nb*16 + lo16;
    bv[nb]  = bias[c];
    gv[nb]  = do_ln ? g[c]  : 1.f;
    bbv[nb] = do_ln ? bb[c] : 0.f;
  }
  #pragma unroll
  for (int mb=0;mb<2;++mb){
    #pragma unroll
    for (int nb=0;nb<2;++nb){
      #pragma unroll
      for (int r=0;r<4;++r) acc[mb][nb][r] = (acc[mb][nb][r] + bv[nb]) * scale;
    }
  }

  if (do_ln){
    #pragma unroll
    for (int mb=0;mb<2;++mb){
      #pragma unroll
      for (int r=0;r<4;++r){
        float s=0.f, ss=0.f;
        #pragma unroll
        for (int nb=0;nb<2;++nb){ float v = acc[mb][nb][r]; s += v; ss += v*v; }
        #pragma unroll
        for (int m=1;m<16;m<<=1){ s += __shfl_xor(s, m, 64); ss += __shfl_xor(ss, m, 64); }
        if (lo16 == 0){
          int row = mb*16 + hi4*4 + r;
          red[row*16 + wid]     = s;
          red[row*16 + 8 + wid] = ss;
        }
      }
    }
    __syncthreads();
    if (tid < 32){
      float s = 0.f, ss = 0.f;
      #pragma unroll
      for (int i=0;i<8;++i){ s += red[tid*16 + i]; ss += red[tid*16 + 8 + i]; }
      float mu = s * (1.f/256.f);
      float var = ss * (1.f/256.f) - mu*mu;
      st[tid*2]   = mu;
      st[tid*2+1] = rsqrtf(var + 1e-5f);
    }
    __syncthreads();
  }

  #pragma unroll
  for (int mb=0;mb<2;++mb){
    #pragma unroll
    for (int r=0;r<4;++r){
      int row = mb*16 + hi4*4 + r;
      float mu = 0.f, rs = 1.f;
      if (do_ln){ mu = st[row*2]; rs = st[row*2+1]; }
      #pragma unroll
      for (int nb=0;nb<2;++nb){
        int c = n0 + nb*16 + lo16;
        float v = acc[mb][nb][r];
        if (do_ln) v = (v - mu) * rs * gv[nb] + bbv[nb];
        if (do_relu) v = fmaxf(v, 0.f);
        out[(b0 + row)*256 + c] = v;
      }
    }
  }
}

// ---------------------------------------------------------------------------
__global__ __launch_bounds__(256)
void k3_softmax(const float* __restrict__ scores, float* __restrict__ wts)
{
  const int b = blockIdx.x, t = threadIdx.x;
  const int wid = t >> 6, lane = t & 63;
  __shared__ float r4[4];
  float sc[4];
  #pragma unroll
  for (int n=0;n<4;++n) sc[n] = scores[(b*4 + n)*256 + t];
  float wsum = 0.f;
  for (int n=0;n<4;++n){
    float m = sc[n];
    #pragma unroll
    for (int k=1;k<64;k<<=1) m = fmaxf(m, __shfl_xor(m, k, 64));
    if (lane == 0) r4[wid] = m;
    __syncthreads();
    m = fmaxf(fmaxf(r4[0], r4[1]), fmaxf(r4[2], r4[3]));
    __syncthreads();
    float ex = __expf(sc[n] - m);
    float s = ex;
    #pragma unroll
    for (int k=1;k<64;k<<=1) s += __shfl_xor(s, k, 64);
    if (lane == 0) r4[wid] = s;
    __syncthreads();
    s = r4[0] + r4[1] + r4[2] + r4[3];
    __syncthreads();
    wsum += ex / s;
  }
  wts[b*256 + t] = wsum * 0.25f;
}

// ---------------------------------------------------------------------------
// k4a: reference's literal einsum 'beh,eh->bh' with weights shape (B,E):
//   combined[b,h] = sum_e eo[b,e,h] * wts_flat[e*256 + h]
// ---------------------------------------------------------------------------
__global__ __launch_bounds__(1024)
void k4a_combined(const float* __restrict__ eo, const float* __restrict__ wts,
                  float* __restrict__ cmb)
{
  __shared__ float part[1024];
  const int b = blockIdx.x, t = threadIdx.x;
  const int c = t >> 8, h = t & 255;
  const float* p = eo + b*65536 + h;
  float s = 0.f;
  #pragma unroll 8
  for (int i = 0; i < 64; ++i){
    int e2 = c*64 + i;
    s += p[e2*256] * wts[e2*256 + h];
  }
  part[t] = s;
  __syncthreads();
  if (t < 256) cmb[b*256 + t] = part[t] + part[t+256] + part[t+512] + part[t+768];
}

extern "C" void kernel_launch(void* const* d_in, const int* in_sizes, int n_in,
                              void* d_out, int out_size, void* d_ws, size_t ws_size,
                              hipStream_t stream)
{
  const float* x    = (const float*)d_in[0];
  const float* te   = (const float*)d_in[1];
  const float* W1   = (const float*)d_in[2];
  const float* b1   = (const float*)d_in[3];
  const float* g1   = (const float*)d_in[4];
  const float* bb1  = (const float*)d_in[5];
  const float* W2   = (const float*)d_in[6];
  const float* b2   = (const float*)d_in[7];
  const float* ipw  = (const float*)d_in[8];
  const float* ipb  = (const float*)d_in[9];
  const float* cw   = (const float*)d_in[10];
  const float* cb   = (const float*)d_in[11];
  const float* cg   = (const float*)d_in[12];
  const float* cbt  = (const float*)d_in[13];

  float* out    = (float*)d_out;        // (256,256)
  float* wts    = out + 65536;          // (256,1,256)
  float* eo     = out + 131072;         // (256,256,256)

  // ws layout: [w1h 32MB | w2h 32MB] | regA 1MB | qWkT 512KB | qbk 4KB
  // regA serves q -> scores -> cmb (lifetimes disjoint: q dead after kqwk;
  // scores dead after k3; cmb written by k4a, read by final k_mini).
  const size_t F16_BYTES = 2ull * 16777216ull * 2;                 // 67,108,864
  const size_t NEED = F16_BYTES + 1048576 + 524288 + 4096;         // 68,685,824
  const bool f16w = ws_size >= NEED;

  f16_t* w1h = (f16_t*)d_ws;
  f16_t* w2h = w1h + 16777216;
  char* tail = f16w ? ((char*)d_ws + F16_BYTES) : (char*)d_ws;
  float* regA  = (float*)tail;                       // 262144 f32
  f16_t* qwkt  = (f16_t*)(tail + 1048576);           // 262144 f16
  float* qbk   = (float*)(tail + 1048576 + 524288);  // 1024 f32
  float* q      = regA;
  float* scores = regA;
  float* cmb    = regA;

  // q = (te @ Wq^T + bq) / 8
  k_mini<<<8, 512, 0, stream>>>(te, ipw, ipb, 0.125f, 0, nullptr, nullptr, 0, q);
  // fold q into Wk: qWkT[b,h,:] and qbk[b,:]
  kqwk<<<256, 256, 0, stream>>>(q, ipw + 65536, ipb, qwkt, qbk);

  if (f16w){
    k0_cvt<<<2048, 256, 0, stream>>>(W1, W2, w1h, w2h);
    k2_fused<1><<<1024, 512, 0, stream>>>(x, w1h, b1, g1, bb1, w2h, b2,
                                          qwkt, qbk, eo, scores);
  } else {
    k2_fused<0><<<1024, 512, 0, stream>>>(x, W1, b1, g1, bb1, W2, b2,
                                          qwkt, qbk, eo, scores);
  }

  // softmax over experts, mean over heads -> weights (out)
  k3_softmax<<<256, 256, 0, stream>>>(scores, wts);
  // combined[b,h] = sum_e eo[b,e,h] * wts[e,h]
  k4a_combined<<<256, 1024, 0, stream>>>(eo, wts, cmb);
  // out = relu(LN(combined @ cw^T + cb))
  k_mini<<<8, 512, 0, stream>>>(cmb, cw, cb, 1.0f, 1, cg, cbt, 1, out);
}

// Round 13
// 153.118 us; speedup vs baseline: 1.0020x; 1.0020x over previous
//
#include <hip/hip_runtime.h>

typedef _Float16 f16_t;
typedef f16_t f16x8 __attribute__((ext_vector_type(8)));
typedef f16_t f16x4 __attribute__((ext_vector_type(4)));
typedef float f32x4 __attribute__((ext_vector_type(4)));

#define MFMA16(a,b,c) __builtin_amdgcn_mfma_f32_16x16x32_f16(a,b,c,0,0,0)
#define VM0 asm volatile("s_waitcnt vmcnt(0)" ::: "memory")
#define VM2 asm volatile("s_waitcnt vmcnt(2)" ::: "memory")

// async global -> LDS, 16B per lane (dest = wave-uniform base + lane*16).
__device__ __forceinline__ void cp16(const void* g, void* l){
  __builtin_amdgcn_global_load_lds(
      (const __attribute__((address_space(1))) void*)g,
      (__attribute__((address_space(3))) void*)l, 16, 0, 0);
}

__device__ __forceinline__ f16x8 cvt8h(float4 a, float4 b){
  f16x8 r;
  r[0]=(f16_t)a.x; r[1]=(f16_t)a.y; r[2]=(f16_t)a.z; r[3]=(f16_t)a.w;
  r[4]=(f16_t)b.x; r[5]=(f16_t)b.y; r[6]=(f16_t)b.z; r[7]=(f16_t)b.w;
  return r;
}

// Stage rows x 256 f32 (row-major) -> LDS f16 [row][256], per-row XOR swizzle
// on 16B chunks: chunk' = chunk ^ (row&7). Row pitch 512B.
template<int NT>
__device__ __forceinline__ void stage_f16(const float* __restrict__ src,
                                          char* dst, int rows, int tid){
  const int nchunk = rows * 32;
  const float4* s4 = reinterpret_cast<const float4*>(src);
  for (int cid = tid; cid < nchunk; cid += NT){
    int r = cid >> 5, c = cid & 31;
    *reinterpret_cast<f16x8*>(dst + r*512 + ((c ^ (r&7))<<4)) = cvt8h(s4[cid*2], s4[cid*2+1]);
  }
}

__device__ __forceinline__ f16x8 ldsA(const char* buf, int row, int c16){
  return *reinterpret_cast<const f16x8*>(buf + row*512 + ((c16 ^ (row&7))<<4));
}

// ---- wave-private W pipeline (bank-conflict-free source permutation) ------
// Lane l loads W[(n0 + (l&15))*256 + kb*32 + (l>>4)*8] into linear LDS slot
// l*16. B-fragment read for lane (lo16,hi4) = addr lane*16 (conflict-free);
// global side: 4 lanes {l, l+16, l+32, l+48} cover one row's 64B segment.
__device__ __forceinline__ void issue_tile(const f16_t* wsrc_lane, int kb, char* wt, int lane){
  const f16_t* s = wsrc_lane + kb*32;
  char* d = wt + (kb&1)*2048 + lane*16;
  cp16(s, d);
  cp16(s + 16*256, d + 1024);
}

// 64x32 C tile, K=256, software-pipelined: consume tile kb (vmcnt(2): tile
// kb+1 stays in flight), then issue tile kb+2 into the slot kb just freed.
__device__ __forceinline__ void gemm_pipe(f32x4 acc[4][2], const char* bufA,
    const f16_t* wsrc_lane, char* wt, int lane, int lo16, int hi4){
  #pragma unroll
  for (int kb = 0; kb < 8; ++kb){
    if (kb < 7) { VM2; } else { VM0; }
    const char* ws = wt + (kb&1)*2048 + lane*16;
    f16x8 bf0 = *reinterpret_cast<const f16x8*>(ws);
    f16x8 bf1 = *reinterpret_cast<const f16x8*>(ws + 1024);
    __builtin_amdgcn_s_setprio(1);
    #pragma unroll
    for (int mb = 0; mb < 4; ++mb){
      f16x8 af = ldsA(bufA, mb*16 + lo16, kb*4 + hi4);
      acc[mb][0] = MFMA16(af, bf0, acc[mb][0]);
      acc[mb][1] = MFMA16(af, bf1, acc[mb][1]);
    }
    __builtin_amdgcn_s_setprio(0);
    __builtin_amdgcn_sched_barrier(0);   // keep the refill below the reads above
    if (kb + 2 < 8) issue_tile(wsrc_lane, kb + 2, wt, lane);
  }
}

// f32-W streaming fallback (only used when ws_size can't hold f16 weights)
__device__ __forceinline__ void gemm_w32(f32x4 acc[4][2], const char* bufA,
    const float* __restrict__ W, int n0, int lo16, int hi4){
  #pragma unroll
  for (int kb = 0; kb < 8; ++kb){
    f16x8 bf[2];
    #pragma unroll
    for (int nb = 0; nb < 2; ++nb){
      const float4* p = reinterpret_cast<const float4*>(W + ((n0 + nb*16 + lo16)<<8) + kb*32 + hi4*8);
      bf[nb] = cvt8h(p[0], p[1]);
    }
    #pragma unroll
    for (int mb = 0; mb < 4; ++mb){
      f16x8 af = ldsA(bufA, mb*16 + lo16, kb*4 + hi4);
      acc[mb][0] = MFMA16(af, bf[0], acc[mb][0]);
      acc[mb][1] = MFMA16(af, bf[1], acc[mb][1]);
    }
  }
}

// ---------------------------------------------------------------------------
// k0_cvt: one-shot f32 -> f16 conversion of W1, W2 into d_ws.
// ---------------------------------------------------------------------------
__global__ __launch_bounds__(256)
void k0_cvt(const float* __restrict__ W1, const float* __restrict__ W2,
            f16_t* __restrict__ w1h, f16_t* __restrict__ w2h)
{
  const long long NG1 = 2097152, NGT = 4194304; // 8-elem groups
  for (long long gidx = (long long)blockIdx.x*256 + threadIdx.x; gidx < NGT;
       gidx += (long long)gridDim.x*256){
    const float4* s; f16_t* d; long long off;
    if (gidx < NG1){ s = (const float4*)W1; d = w1h; off = gidx; }
    else { s = (const float4*)W2; d = w2h; off = gidx - NG1; }
    *reinterpret_cast<f16x8*>(d + off*8) = cvt8h(s[off*2], s[off*2+1]);
  }
}

// ---------------------------------------------------------------------------
// kqwk2: MFMA replacement for the old kqwk (which walked Wk COLUMNS with
// 16.7M strided scalar L2 loads, ~10-14us). Computes, per (n, h-chunk):
//   qWkT[b][h][n] = sum_d q[b, n*64+d] * Wk[n*64+d, h]    (C = qA @ wkT^T)
//   qbk[b][n]     = sum_d q[b, n*64+d] * bk[n*64+d]       (hc==0 blocks)
// grid 16 = (n 0..3) x (hc 0..3); block 256 = 4 waves; Wk chunk staged
// TRANSPOSED to LDS once (coalesced global reads), K=64 = 2 MFMA steps.
// ---------------------------------------------------------------------------
__global__ __launch_bounds__(256)
void kqwk2(const float* __restrict__ q, const float* __restrict__ Wk,
           const float* __restrict__ ipb, f16_t* __restrict__ qWkT,
           float* __restrict__ qbk)
{
  __shared__ __align__(16) char lds[41216];
  char* qA   = lds;                       // [256][64] f16, pitch 128B, swizzled
  char* wkT  = lds + 32768;               // [64 h][64 d] f16, pitch 128B, swizzled
  float* sipb = (float*)(lds + 40960);    // [64]

  const int bx = blockIdx.x;
  const int n  = bx >> 2, hc = bx & 3;
  const int t  = threadIdx.x;
  const int lane = t & 63, wid = t >> 6;
  const int lo16 = lane & 15, hi4 = lane >> 4;
  const int m0 = wid * 64;

  // stage qA: q[:, n*64 .. n*64+64) -> f16, swizzle chunk c in [0,8)
  {
    const float4* s4 = reinterpret_cast<const float4*>(q);
    for (int cid = t; cid < 2048; cid += 256){
      int b = cid >> 3, c = cid & 7;
      int si = b*64 + n*16 + c*2;
      *reinterpret_cast<f16x8*>(qA + b*128 + ((c ^ (b&7))<<4)) = cvt8h(s4[si], s4[si+1]);
    }
  }
  // stage wkT transposed: wkT[hh][d] = Wk[n*64+d][hc*64+hh] (coalesced reads)
  for (int idx = t; idx < 4096; idx += 256){
    int d = idx >> 6, hh = idx & 63;
    float v = Wk[(n*64 + d)*256 + hc*64 + hh];
    *reinterpret_cast<f16_t*>(wkT + hh*128 + (((d>>3) ^ (hh&7))<<4) + (d&7)*2) = (f16_t)v;
  }
  if (hc == 0 && t < 64) sipb[t] = ipb[256 + n*64 + t];
  __syncthreads();

  f32x4 acc[4][4];
  #pragma unroll
  for (int mb=0;mb<4;++mb){
    #pragma unroll
    for (int nb=0;nb<4;++nb) acc[mb][nb] = (f32x4)0.0f;
  }

  #pragma unroll
  for (int kb = 0; kb < 2; ++kb){
    int c16 = kb*4 + hi4;
    f16x8 bf[4], af[4];
    #pragma unroll
    for (int nb = 0; nb < 4; ++nb){
      int h = nb*16 + lo16;
      bf[nb] = *reinterpret_cast<const f16x8*>(wkT + h*128 + ((c16 ^ (h&7))<<4));
    }
    #pragma unroll
    for (int mb = 0; mb < 4; ++mb){
      int row = m0 + mb*16 + lo16;
      af[mb] = *reinterpret_cast<const f16x8*>(qA + row*128 + ((c16 ^ (row&7))<<4));
    }
    #pragma unroll
    for (int mb = 0; mb < 4; ++mb){
      #pragma unroll
      for (int nb = 0; nb < 4; ++nb) acc[mb][nb] = MFMA16(af[mb], bf[nb], acc[mb][nb]);
    }
  }

  // store: C row = b (m0 + mb*16 + hi4*4 + r), col = h (nb*16 + lo16)
  #pragma unroll
  for (int mb=0;mb<4;++mb){
    #pragma unroll
    for (int r=0;r<4;++r){
      int b = m0 + mb*16 + hi4*4 + r;
      #pragma unroll
      for (int nb=0;nb<4;++nb){
        int h = hc*64 + nb*16 + lo16;
        qWkT[(b*256 + h)*4 + n] = (f16_t)acc[mb][nb][r];
      }
    }
  }

  if (hc == 0){
    // qbk[b][n] from staged qA (f16) and sipb
    int b = t;
    float s = 0.f;
    #pragma unroll 8
    for (int d = 0; d < 64; ++d){
      f16_t qv = *reinterpret_cast<const f16_t*>(qA + b*128 + (((d>>3) ^ (b&7))<<4) + (d&7)*2);
      s += (float)qv * sipb[d];
    }
    qbk[b*4 + n] = s;
  }
}

// ---------------------------------------------------------------------------
// k2_fused: per (expert e, 64-row batch tile):
//   h = x@W1[e]^T + b1 ; LN ; relu -> hr(f16 LDS) ; eo = hr@W2[e]^T + b2 ->
//   global f32 ; scores partials via qWkT dot (GEMM3 eliminated).
// grid 1024 XCD-swizzled (xcd=l&7 -> e=xcd*32+(l>>5), btile=(l>>3)&3);
// block 512 = 8 col-waves. LDS 74.2KB -> 2 blocks/CU.
// ---------------------------------------------------------------------------
template<int W16>
__global__ __launch_bounds__(512, 4)
void k2_fused(const float* __restrict__ x, const void* __restrict__ W1v,
              const float* __restrict__ b1, const float* __restrict__ g1,
              const float* __restrict__ bb1, const void* __restrict__ W2v,
              const float* __restrict__ b2, const f16_t* __restrict__ qWkT,
              const float* __restrict__ qbk,
              float* __restrict__ eo_out, float* __restrict__ scores)
{
  __shared__ __align__(16) char lds[74240];
  char* bufA = lds;                    // 32KB: x(f16) -> hr(f16)
  float* red = (float*)(lds + 32768);  // 8KB: LN [64][16] / scores [64][8][4]
  float* st  = (float*)(lds + 40960);  // [64][2] = 512B
  char* wpipe = lds + 41472;           // 8 waves x 2 slots x 2KB = 32KB

  const int l = blockIdx.x;
  const int e    = (l & 7) * 32 + (l >> 5);
  const int b0   = ((l >> 3) & 3) * 64;
  const int tid = threadIdx.x;
  const int lane = tid & 63, wid = tid >> 6;
  const int lo16 = lane & 15, hi4 = lane >> 4;
  const int n0 = wid * 32;
  char* wt = wpipe + wid*4096;

  // bank-conflict-free per-lane source permutation (see issue_tile comment)
  const int pl = (n0 + (lane & 15))*256 + (lane >> 4)*8;
  const f16_t* src1 = nullptr; const f16_t* src2 = nullptr;
  if (W16){
    src1 = (const f16_t*)W1v + e*65536 + pl;
    src2 = (const f16_t*)W2v + e*65536 + pl;
    issue_tile(src1, 0, wt, lane);       // G1 prefetch hides under x-stage
    issue_tile(src1, 1, wt, lane);
  }

  stage_f16<512>(x + b0*256, bufA, 64, tid);
  __syncthreads();

  f32x4 acc[4][2];
  #pragma unroll
  for (int mb=0;mb<4;++mb){
    #pragma unroll
    for (int nb=0;nb<2;++nb) acc[mb][nb] = (f32x4)0.0f;
  }

  if (W16) gemm_pipe(acc, bufA, src1, wt, lane, lo16, hi4);
  else     gemm_w32(acc, bufA, (const float*)W1v + e*65536, n0, lo16, hi4);

  if (W16){                              // G2 prefetch hides under LN phase
    issue_tile(src2, 0, wt, lane);
    issue_tile(src2, 1, wt, lane);
  }

  float b1v[2], g1v[2], bbv[2], b2v[2];
  #pragma unroll
  for (int nb=0;nb<2;++nb){
    int c = n0 + nb*16 + lo16;
    b1v[nb] = b1[e*256 + c];
    g1v[nb] = g1[e*256 + c];
    bbv[nb] = bb1[e*256 + c];
    b2v[nb] = b2[e*256 + c];
  }
  #pragma unroll
  for (int mb=0;mb<4;++mb){
    #pragma unroll
    for (int nb=0;nb<2;++nb){
      #pragma unroll
      for (int r=0;r<4;++r) acc[mb][nb][r] += b1v[nb];
    }
  }

  // LN stats: per-row sum/sumsq across the 8 column-waves
  #pragma unroll
  for (int mb=0;mb<4;++mb){
    #pragma unroll
    for (int r=0;r<4;++r){
      float s=0.f, ss=0.f;
      #pragma unroll
      for (int nb=0;nb<2;++nb){ float v = acc[mb][nb][r]; s += v; ss += v*v; }
      #pragma unroll
      for (int m=1;m<16;m<<=1){ s += __shfl_xor(s, m, 64); ss += __shfl_xor(ss, m, 64); }
      if (lo16 == 0){
        int row = mb*16 + hi4*4 + r;
        red[row*16 + wid]     = s;
        red[row*16 + 8 + wid] = ss;
      }
    }
  }
  __syncthreads();   // also: all waves done reading x from bufA
  if (tid < 64){
    float s  = 0.f, ss = 0.f;
    #pragma unroll
    for (int i=0;i<8;++i){ s += red[tid*16 + i]; ss += red[tid*16 + 8 + i]; }
    float mu = s * (1.f/256.f);
    float var = ss * (1.f/256.f) - mu*mu;
    st[tid*2]   = mu;
    st[tid*2+1] = rsqrtf(var + 1e-5f);
  }
  __syncthreads();

  // LN + relu -> hr (f16) back into bufA
  #pragma unroll
  for (int mb=0;mb<4;++mb){
    #pragma unroll
    for (int r=0;r<4;++r){
      int row = mb*16 + hi4*4 + r;
      float mu = st[row*2], rs = st[row*2+1];
      #pragma unroll
      for (int nb=0;nb<2;++nb){
        int c = n0 + nb*16 + lo16;
        float v = (acc[mb][nb][r] - mu) * rs * g1v[nb] + bbv[nb];
        v = fmaxf(v, 0.f);
        int off = row*512 + (((c>>3) ^ (row&7))<<4) + (c&7)*2;
        *reinterpret_cast<f16_t*>(bufA + off) = (f16_t)v;
      }
    }
  }
  __syncthreads();

  // GEMM2: eo = hr @ W2[e]^T + b2
  #pragma unroll
  for (int mb=0;mb<4;++mb){
    #pragma unroll
    for (int nb=0;nb<2;++nb) acc[mb][nb] = (f32x4)0.0f;
  }
  if (W16) gemm_pipe(acc, bufA, src2, wt, lane, lo16, hi4);
  else     gemm_w32(acc, bufA, (const float*)W2v + e*65536, n0, lo16, hi4);

  // epilogue: eo store + scores partials (no bufA write, no barrier needed)
  #pragma unroll
  for (int mb=0;mb<4;++mb){
    #pragma unroll
    for (int r=0;r<4;++r){
      int row = mb*16 + hi4*4 + r;
      int b = b0 + row;
      float p0=0.f, p1=0.f, p2=0.f, p3=0.f;
      #pragma unroll
      for (int nb=0;nb<2;++nb){
        int c = n0 + nb*16 + lo16;
        float v = acc[mb][nb][r] + b2v[nb];
        eo_out[(b*256 + e)*256 + c] = v;
        f16x4 qk = *reinterpret_cast<const f16x4*>(qWkT + (b*256 + c)*4);
        p0 += v * (float)qk[0];
        p1 += v * (float)qk[1];
        p2 += v * (float)qk[2];
        p3 += v * (float)qk[3];
      }
      #pragma unroll
      for (int m=1;m<16;m<<=1){
        p0 += __shfl_xor(p0, m, 64); p1 += __shfl_xor(p1, m, 64);
        p2 += __shfl_xor(p2, m, 64); p3 += __shfl_xor(p3, m, 64);
      }
      if (lo16 == 0){
        red[row*32 + wid*4 + 0] = p0;
        red[row*32 + wid*4 + 1] = p1;
        red[row*32 + wid*4 + 2] = p2;
        red[row*32 + wid*4 + 3] = p3;
      }
    }
  }
  __syncthreads();
  if (tid < 256){
    int row = tid >> 2, n = tid & 3;
    float sc = 0.f;
    #pragma unroll
    for (int w=0;w<8;++w) sc += red[row*32 + w*4 + n];
    scores[((b0 + row)*4 + n)*256 + e] = sc + qbk[(b0 + row)*4 + n];
  }
}

// ---------------------------------------------------------------------------
// k_mini: out = act( maybeLN( (A @ W^T + bias) * scale ) ), 256x256x256, f16.
// grid 8 (32-row tiles), block 512 = 8 col-waves, acc[2][2].
// ---------------------------------------------------------------------------
__global__ __launch_bounds__(512, 4)
void k_mini(const float* __restrict__ A, const float* __restrict__ W,
            const float* __restrict__ bias, float scale, int do_ln,
            const float* __restrict__ g, const float* __restrict__ bb,
            int do_relu, float* __restrict__ out)
{
  __shared__ __align__(16) char lds[18688];
  char* bufA = lds;                    // 16KB: A rows (f16)
  float* red = (float*)(lds + 16384);  // [32][16] = 2KB
  float* st  = (float*)(lds + 18432);  // [32][2]  = 256B

  const int b0 = blockIdx.x * 32;
  const int tid = threadIdx.x;
  const int lane = tid & 63, wid = tid >> 6;
  const int lo16 = lane & 15, hi4 = lane >> 4;
  const int n0 = wid * 32;

  stage_f16<512>(A + b0*256, bufA, 32, tid);
  __syncthreads();

  f32x4 acc[2][2];
  #pragma unroll
  for (int mb=0;mb<2;++mb){
    #pragma unroll
    for (int nb=0;nb<2;++nb) acc[mb][nb] = (f32x4)0.0f;
  }
  #pragma unroll
  for (int kb = 0; kb < 8; ++kb){
    f16x8 bf[2];
    #pragma unroll
    for (int nb = 0; nb < 2; ++nb){
      const float4* p = reinterpret_cast<const float4*>(W + ((n0 + nb*16 + lo16)<<8) + kb*32 + hi4*8);
      bf[nb] = cvt8h(p[0], p[1]);
    }
    #pragma unroll
    for (int mb = 0; mb < 2; ++mb){
      f16x8 af = ldsA(bufA, mb*16 + lo16, kb*4 + hi4);
      acc[mb][0] = MFMA16(af, bf[0], acc[mb][0]);
      acc[mb][1] = MFMA16(af, bf[1], acc[mb][1]);
    }
  }

  float bv[2], gv[2], bbv[2];
  #pragma unroll
  for (int nb=0;nb<2;++nb){
    int c = n0 + nb*16 + lo16;
    bv[nb]  = bias[c];
    gv[nb]  = do_ln ? g[c]  : 1.f;
    bbv[nb] = do_ln ? bb[c] : 0.f;
  }
  #pragma unroll
  for (int mb=0;mb<2;++mb){
    #pragma unroll
    for (int nb=0;nb<2;++nb){
      #pragma unroll
      for (int r=0;r<4;++r) acc[mb][nb][r] = (acc[mb][nb][r] + bv[nb]) * scale;
    }
  }

  if (do_ln){
    #pragma unroll
    for (int mb=0;mb<2;++mb){
      #pragma unroll
      for (int r=0;r<4;++r){
        float s=0.f, ss=0.f;
        #pragma unroll
        for (int nb=0;nb<2;++nb){ float v = acc[mb][nb][r]; s += v; ss += v*v; }
        #pragma unroll
        for (int m=1;m<16;m<<=1){ s += __shfl_xor(s, m, 64); ss += __shfl_xor(ss, m, 64); }
        if (lo16 == 0){
          int row = mb*16 + hi4*4 + r;
          red[row*16 + wid]     = s;
          red[row*16 + 8 + wid] = ss;
        }
      }
    }
    __syncthreads();
    if (tid < 32){
      float s = 0.f, ss = 0.f;
      #pragma unroll
      for (int i=0;i<8;++i){ s += red[tid*16 + i]; ss += red[tid*16 + 8 + i]; }
      float mu = s * (1.f/256.f);
      float var = ss * (1.f/256.f) - mu*mu;
      st[tid*2]   = mu;
      st[tid*2+1] = rsqrtf(var + 1e-5f);
    }
    __syncthreads();
  }

  #pragma unroll
  for (int mb=0;mb<2;++mb){
    #pragma unroll
    for (int r=0;r<4;++r){
      int row = mb*16 + hi4*4 + r;
      float mu = 0.f, rs = 1.f;
      if (do_ln){ mu = st[row*2]; rs = st[row*2+1]; }
      #pragma unroll
      for (int nb=0;nb<2;++nb){
        int c = n0 + nb*16 + lo16;
        float v = acc[mb][nb][r];
        if (do_ln) v = (v - mu) * rs * gv[nb] + bbv[nb];
        if (do_relu) v = fmaxf(v, 0.f);
        out[(b0 + row)*256 + c] = v;
      }
    }
  }
}

// ---------------------------------------------------------------------------
__global__ __launch_bounds__(256)
void k3_softmax(const float* __restrict__ scores, float* __restrict__ wts)
{
  const int b = blockIdx.x, t = threadIdx.x;
  const int wid = t >> 6, lane = t & 63;
  __shared__ float r4[4];
  float sc[4];
  #pragma unroll
  for (int n=0;n<4;++n) sc[n] = scores[(b*4 + n)*256 + t];
  float wsum = 0.f;
  for (int n=0;n<4;++n){
    float m = sc[n];
    #pragma unroll
    for (int k=1;k<64;k<<=1) m = fmaxf(m, __shfl_xor(m, k, 64));
    if (lane == 0) r4[wid] = m;
    __syncthreads();
    m = fmaxf(fmaxf(r4[0], r4[1]), fmaxf(r4[2], r4[3]));
    __syncthreads();
    float ex = __expf(sc[n] - m);
    float s = ex;
    #pragma unroll
    for (int k=1;k<64;k<<=1) s += __shfl_xor(s, k, 64);
    if (lane == 0) r4[wid] = s;
    __syncthreads();
    s = r4[0] + r4[1] + r4[2] + r4[3];
    __syncthreads();
    wsum += ex / s;
  }
  wts[b*256 + t] = wsum * 0.25f;
}

// ---------------------------------------------------------------------------
// k4a: reference's literal einsum 'beh,eh->bh' with weights shape (B,E):
//   combined[b,h] = sum_e eo[b,e,h] * wts_flat[e*256 + h]
// ---------------------------------------------------------------------------
__global__ __launch_bounds__(1024)
void k4a_combined(const float* __restrict__ eo, const float* __restrict__ wts,
                  float* __restrict__ cmb)
{
  __shared__ float part[1024];
  const int b = blockIdx.x, t = threadIdx.x;
  const int c = t >> 8, h = t & 255;
  const float* p = eo + b*65536 + h;
  float s = 0.f;
  #pragma unroll 8
  for (int i = 0; i < 64; ++i){
    int e2 = c*64 + i;
    s += p[e2*256] * wts[e2*256 + h];
  }
  part[t] = s;
  __syncthreads();
  if (t < 256) cmb[b*256 + t] = part[t] + part[t+256] + part[t+512] + part[t+768];
}

extern "C" void kernel_launch(void* const* d_in, const int* in_sizes, int n_in,
                              void* d_out, int out_size, void* d_ws, size_t ws_size,
                              hipStream_t stream)
{
  const float* x    = (const float*)d_in[0];
  const float* te   = (const float*)d_in[1];
  const float* W1   = (const float*)d_in[2];
  const float* b1   = (const float*)d_in[3];
  const float* g1   = (const float*)d_in[4];
  const float* bb1  = (const float*)d_in[5];
  const float* W2   = (const float*)d_in[6];
  const float* b2   = (const float*)d_in[7];
  const float* ipw  = (const float*)d_in[8];
  const float* ipb  = (const float*)d_in[9];
  const float* cw   = (const float*)d_in[10];
  const float* cb   = (const float*)d_in[11];
  const float* cg   = (const float*)d_in[12];
  const float* cbt  = (const float*)d_in[13];

  float* out    = (float*)d_out;        // (256,256)
  float* wts    = out + 65536;          // (256,1,256)
  float* eo     = out + 131072;         // (256,256,256)

  // ws layout: [w1h 32MB | w2h 32MB] | regA 1MB | qWkT 512KB | qbk 4KB
  // regA serves q -> scores -> cmb (lifetimes disjoint).
  const size_t F16_BYTES = 2ull * 16777216ull * 2;                 // 67,108,864
  const size_t NEED = F16_BYTES + 1048576 + 524288 + 4096;         // 68,685,824
  const bool f16w = ws_size >= NEED;

  f16_t* w1h = (f16_t*)d_ws;
  f16_t* w2h = w1h + 16777216;
  char* tail = f16w ? ((char*)d_ws + F16_BYTES) : (char*)d_ws;
  float* regA  = (float*)tail;                       // 262144 f32
  f16_t* qwkt  = (f16_t*)(tail + 1048576);           // 262144 f16
  float* qbk   = (float*)(tail + 1048576 + 524288);  // 1024 f32
  float* q      = regA;
  float* scores = regA;
  float* cmb    = regA;

  // q = (te @ Wq^T + bq) / 8
  k_mini<<<8, 512, 0, stream>>>(te, ipw, ipb, 0.125f, 0, nullptr, nullptr, 0, q);
  // fold q into Wk via MFMA micro-kernel: qWkT[b,h,:] and qbk[b,:]
  kqwk2<<<16, 256, 0, stream>>>(q, ipw + 65536, ipb, qwkt, qbk);

  if (f16w){
    k0_cvt<<<2048, 256, 0, stream>>>(W1, W2, w1h, w2h);
    k2_fused<1><<<1024, 512, 0, stream>>>(x, w1h, b1, g1, bb1, w2h, b2,
                                          qwkt, qbk, eo, scores);
  } else {
    k2_fused<0><<<1024, 512, 0, stream>>>(x, W1, b1, g1, bb1, W2, b2,
                                          qwkt, qbk, eo, scores);
  }

  // softmax over experts, mean over heads -> weights (out)
  k3_softmax<<<256, 256, 0, stream>>>(scores, wts);
  // combined[b,h] = sum_e eo[b,e,h] * wts[e,h]
  k4a_combined<<<256, 1024, 0, stream>>>(eo, wts, cmb);
  // out = relu(LN(combined @ cw^T + cb))
  k_mini<<<8, 512, 0, stream>>>(cmb, cw, cb, 1.0f, 1, cg, cbt, 1, out);
}

// Round 14
// 151.221 us; speedup vs baseline: 1.0146x; 1.0125x over previous
//
#include <hip/hip_runtime.h>

typedef _Float16 f16_t;
typedef f16_t f16x8 __attribute__((ext_vector_type(8)));
typedef f16_t f16x4 __attribute__((ext_vector_type(4)));
typedef float f32x4 __attribute__((ext_vector_type(4)));

#define MFMA16(a,b,c) __builtin_amdgcn_mfma_f32_16x16x32_f16(a,b,c,0,0,0)
#define VM0 asm volatile("s_waitcnt vmcnt(0)" ::: "memory")
#define VM2 asm volatile("s_waitcnt vmcnt(2)" ::: "memory")

// async global -> LDS, 16B per lane (dest = wave-uniform base + lane*16).
__device__ __forceinline__ void cp16(const void* g, void* l){
  __builtin_amdgcn_global_load_lds(
      (const __attribute__((address_space(1))) void*)g,
      (__attribute__((address_space(3))) void*)l, 16, 0, 0);
}

__device__ __forceinline__ f16x8 cvt8h(float4 a, float4 b){
  f16x8 r;
  r[0]=(f16_t)a.x; r[1]=(f16_t)a.y; r[2]=(f16_t)a.z; r[3]=(f16_t)a.w;
  r[4]=(f16_t)b.x; r[5]=(f16_t)b.y; r[6]=(f16_t)b.z; r[7]=(f16_t)b.w;
  return r;
}

// Stage rows x 256 f32 (row-major) -> LDS f16 [row][256], per-row XOR swizzle
// on 16B chunks: chunk' = chunk ^ (row&7). Row pitch 512B.
template<int NT>
__device__ __forceinline__ void stage_f16(const float* __restrict__ src,
                                          char* dst, int rows, int tid){
  const int nchunk = rows * 32;
  const float4* s4 = reinterpret_cast<const float4*>(src);
  for (int cid = tid; cid < nchunk; cid += NT){
    int r = cid >> 5, c = cid & 31;
    *reinterpret_cast<f16x8*>(dst + r*512 + ((c ^ (r&7))<<4)) = cvt8h(s4[cid*2], s4[cid*2+1]);
  }
}

__device__ __forceinline__ f16x8 ldsA(const char* buf, int row, int c16){
  return *reinterpret_cast<const f16x8*>(buf + row*512 + ((c16 ^ (row&7))<<4));
}

// ---- wave-private W pipeline (ROUND-8 configuration, the 84.6us one) ------
// Lane l loads W[(n0 + (l>>2))*256 + kb*32 + (l&3)*8] into linear LDS slot
// l*16: row r=l>>2 occupies bytes r*64 + (l&3)*16 of the 1KB region; rows
// +16 in region +1024. B-fragment read: region nb*1024 + lo16*64 + hi4*16.
__device__ __forceinline__ void issue_tile(const f16_t* wsrc_lane, int kb, char* wt, int lane){
  const f16_t* s = wsrc_lane + kb*32;
  char* d = wt + (kb&1)*2048 + lane*16;
  cp16(s, d);
  cp16(s + 16*256, d + 1024);
}

// 64x32 C tile, K=256, software-pipelined: consume tile kb (vmcnt(2): tile
// kb+1 stays in flight), then issue tile kb+2 into the slot kb just freed.
// NO setprio (m190 + r11's +8us regression in this lockstep structure).
__device__ __forceinline__ void gemm_pipe(f32x4 acc[4][2], const char* bufA,
    const f16_t* wsrc_lane, char* wt, int lane, int lo16, int hi4){
  #pragma unroll
  for (int kb = 0; kb < 8; ++kb){
    if (kb < 7) { VM2; } else { VM0; }
    const char* ws = wt + (kb&1)*2048 + lo16*64 + hi4*16;
    f16x8 bf0 = *reinterpret_cast<const f16x8*>(ws);
    f16x8 bf1 = *reinterpret_cast<const f16x8*>(ws + 1024);
    #pragma unroll
    for (int mb = 0; mb < 4; ++mb){
      f16x8 af = ldsA(bufA, mb*16 + lo16, kb*4 + hi4);
      acc[mb][0] = MFMA16(af, bf0, acc[mb][0]);
      acc[mb][1] = MFMA16(af, bf1, acc[mb][1]);
    }
    __builtin_amdgcn_sched_barrier(0);   // keep the refill below the reads above
    if (kb + 2 < 8) issue_tile(wsrc_lane, kb + 2, wt, lane);
  }
}

// f32-W streaming fallback (only used when ws_size can't hold f16 weights)
__device__ __forceinline__ void gemm_w32(f32x4 acc[4][2], const char* bufA,
    const float* __restrict__ W, int n0, int lo16, int hi4){
  #pragma unroll
  for (int kb = 0; kb < 8; ++kb){
    f16x8 bf[2];
    #pragma unroll
    for (int nb = 0; nb < 2; ++nb){
      const float4* p = reinterpret_cast<const float4*>(W + ((n0 + nb*16 + lo16)<<8) + kb*32 + hi4*8);
      bf[nb] = cvt8h(p[0], p[1]);
    }
    #pragma unroll
    for (int mb = 0; mb < 4; ++mb){
      f16x8 af = ldsA(bufA, mb*16 + lo16, kb*4 + hi4);
      acc[mb][0] = MFMA16(af, bf[0], acc[mb][0]);
      acc[mb][1] = MFMA16(af, bf[1], acc[mb][1]);
    }
  }
}

// ---------------------------------------------------------------------------
// k0_cvt: one-shot f32 -> f16 conversion of W1, W2 into d_ws.
// ---------------------------------------------------------------------------
__global__ __launch_bounds__(256)
void k0_cvt(const float* __restrict__ W1, const float* __restrict__ W2,
            f16_t* __restrict__ w1h, f16_t* __restrict__ w2h)
{
  const long long NG1 = 2097152, NGT = 4194304; // 8-elem groups
  for (long long gidx = (long long)blockIdx.x*256 + threadIdx.x; gidx < NGT;
       gidx += (long long)gridDim.x*256){
    const float4* s; f16_t* d; long long off;
    if (gidx < NG1){ s = (const float4*)W1; d = w1h; off = gidx; }
    else { s = (const float4*)W2; d = w2h; off = gidx - NG1; }
    *reinterpret_cast<f16x8*>(d + off*8) = cvt8h(s[off*2], s[off*2+1]);
  }
}

// ---------------------------------------------------------------------------
// kqwk2: per (n, h-chunk) MFMA micro-kernel:
//   qWkT[b][h][n] = sum_d q[b, n*64+d] * Wk[n*64+d, h]
//   qbk[b][n]     = sum_d q[b, n*64+d] * bk[n*64+d]       (hc==0 blocks)
// ---------------------------------------------------------------------------
__global__ __launch_bounds__(256)
void kqwk2(const float* __restrict__ q, const float* __restrict__ Wk,
           const float* __restrict__ ipb, f16_t* __restrict__ qWkT,
           float* __restrict__ qbk)
{
  __shared__ __align__(16) char lds[41216];
  char* qA   = lds;                       // [256][64] f16, pitch 128B, swizzled
  char* wkT  = lds + 32768;               // [64 h][64 d] f16, pitch 128B, swizzled
  float* sipb = (float*)(lds + 40960);    // [64]

  const int bx = blockIdx.x;
  const int n  = bx >> 2, hc = bx & 3;
  const int t  = threadIdx.x;
  const int lane = t & 63, wid = t >> 6;
  const int lo16 = lane & 15, hi4 = lane >> 4;
  const int m0 = wid * 64;

  {
    const float4* s4 = reinterpret_cast<const float4*>(q);
    for (int cid = t; cid < 2048; cid += 256){
      int b = cid >> 3, c = cid & 7;
      int si = b*64 + n*16 + c*2;
      *reinterpret_cast<f16x8*>(qA + b*128 + ((c ^ (b&7))<<4)) = cvt8h(s4[si], s4[si+1]);
    }
  }
  for (int idx = t; idx < 4096; idx += 256){
    int d = idx >> 6, hh = idx & 63;
    float v = Wk[(n*64 + d)*256 + hc*64 + hh];
    *reinterpret_cast<f16_t*>(wkT + hh*128 + (((d>>3) ^ (hh&7))<<4) + (d&7)*2) = (f16_t)v;
  }
  if (hc == 0 && t < 64) sipb[t] = ipb[256 + n*64 + t];
  __syncthreads();

  f32x4 acc[4][4];
  #pragma unroll
  for (int mb=0;mb<4;++mb){
    #pragma unroll
    for (int nb=0;nb<4;++nb) acc[mb][nb] = (f32x4)0.0f;
  }

  #pragma unroll
  for (int kb = 0; kb < 2; ++kb){
    int c16 = kb*4 + hi4;
    f16x8 bf[4], af[4];
    #pragma unroll
    for (int nb = 0; nb < 4; ++nb){
      int h = nb*16 + lo16;
      bf[nb] = *reinterpret_cast<const f16x8*>(wkT + h*128 + ((c16 ^ (h&7))<<4));
    }
    #pragma unroll
    for (int mb = 0; mb < 4; ++mb){
      int row = m0 + mb*16 + lo16;
      af[mb] = *reinterpret_cast<const f16x8*>(qA + row*128 + ((c16 ^ (row&7))<<4));
    }
    #pragma unroll
    for (int mb = 0; mb < 4; ++mb){
      #pragma unroll
      for (int nb = 0; nb < 4; ++nb) acc[mb][nb] = MFMA16(af[mb], bf[nb], acc[mb][nb]);
    }
  }

  #pragma unroll
  for (int mb=0;mb<4;++mb){
    #pragma unroll
    for (int r=0;r<4;++r){
      int b = m0 + mb*16 + hi4*4 + r;
      #pragma unroll
      for (int nb=0;nb<4;++nb){
        int h = hc*64 + nb*16 + lo16;
        qWkT[(b*256 + h)*4 + n] = (f16_t)acc[mb][nb][r];
      }
    }
  }

  if (hc == 0){
    int b = t;
    float s = 0.f;
    #pragma unroll 8
    for (int d = 0; d < 64; ++d){
      f16_t qv = *reinterpret_cast<const f16_t*>(qA + b*128 + (((d>>3) ^ (b&7))<<4) + (d&7)*2);
      s += (float)qv * sipb[d];
    }
    qbk[b*4 + n] = s;
  }
}

// ---------------------------------------------------------------------------
// k2_fused: per (expert e, 64-row batch tile):
//   h = x@W1[e]^T + b1 ; LN ; relu -> hr(f16 LDS) ; eo = hr@W2[e]^T + b2 ->
//   global f32 ; scores partials via qWkT dot (GEMM3 eliminated).
// grid 1024 XCD-swizzled; block 512 = 8 col-waves. Round-8 pipe (no setprio,
// lane>>2 permutation). LDS 74.2KB -> 2 blocks/CU.
// ---------------------------------------------------------------------------
template<int W16>
__global__ __launch_bounds__(512, 4)
void k2_fused(const float* __restrict__ x, const void* __restrict__ W1v,
              const float* __restrict__ b1, const float* __restrict__ g1,
              const float* __restrict__ bb1, const void* __restrict__ W2v,
              const float* __restrict__ b2, const f16_t* __restrict__ qWkT,
              const float* __restrict__ qbk,
              float* __restrict__ eo_out, float* __restrict__ scores)
{
  __shared__ __align__(16) char lds[74240];
  char* bufA = lds;                    // 32KB: x(f16) -> hr(f16)
  float* red = (float*)(lds + 32768);  // 8KB: LN [64][16] / scores [64][8][4]
  float* st  = (float*)(lds + 40960);  // [64][2] = 512B
  char* wpipe = lds + 41472;           // 8 waves x 2 slots x 2KB = 32KB

  const int l = blockIdx.x;
  const int e    = (l & 7) * 32 + (l >> 5);
  const int b0   = ((l >> 3) & 3) * 64;
  const int tid = threadIdx.x;
  const int lane = tid & 63, wid = tid >> 6;
  const int lo16 = lane & 15, hi4 = lane >> 4;
  const int n0 = wid * 32;
  char* wt = wpipe + wid*4096;

  // round-8 per-lane source offset (see issue_tile comment)
  const int pl = (n0 + (lane >> 2))*256 + (lane & 3)*8;
  const f16_t* src1 = nullptr; const f16_t* src2 = nullptr;
  if (W16){
    src1 = (const f16_t*)W1v + e*65536 + pl;
    src2 = (const f16_t*)W2v + e*65536 + pl;
    issue_tile(src1, 0, wt, lane);       // G1 prefetch hides under x-stage
    issue_tile(src1, 1, wt, lane);
  }

  stage_f16<512>(x + b0*256, bufA, 64, tid);
  __syncthreads();

  f32x4 acc[4][2];
  #pragma unroll
  for (int mb=0;mb<4;++mb){
    #pragma unroll
    for (int nb=0;nb<2;++nb) acc[mb][nb] = (f32x4)0.0f;
  }

  if (W16) gemm_pipe(acc, bufA, src1, wt, lane, lo16, hi4);
  else     gemm_w32(acc, bufA, (const float*)W1v + e*65536, n0, lo16, hi4);

  if (W16){                              // G2 prefetch hides under LN phase
    issue_tile(src2, 0, wt, lane);
    issue_tile(src2, 1, wt, lane);
  }

  float b1v[2], g1v[2], bbv[2], b2v[2];
  #pragma unroll
  for (int nb=0;nb<2;++nb){
    int c = n0 + nb*16 + lo16;
    b1v[nb] = b1[e*256 + c];
    g1v[nb] = g1[e*256 + c];
    bbv[nb] = bb1[e*256 + c];
    b2v[nb] = b2[e*256 + c];
  }
  #pragma unroll
  for (int mb=0;mb<4;++mb){
    #pragma unroll
    for (int nb=0;nb<2;++nb){
      #pragma unroll
      for (int r=0;r<4;++r) acc[mb][nb][r] += b1v[nb];
    }
  }

  // LN stats: per-row sum/sumsq across the 8 column-waves
  #pragma unroll
  for (int mb=0;mb<4;++mb){
    #pragma unroll
    for (int r=0;r<4;++r){
      float s=0.f, ss=0.f;
      #pragma unroll
      for (int nb=0;nb<2;++nb){ float v = acc[mb][nb][r]; s += v; ss += v*v; }
      #pragma unroll
      for (int m=1;m<16;m<<=1){ s += __shfl_xor(s, m, 64); ss += __shfl_xor(ss, m, 64); }
      if (lo16 == 0){
        int row = mb*16 + hi4*4 + r;
        red[row*16 + wid]     = s;
        red[row*16 + 8 + wid] = ss;
      }
    }
  }
  __syncthreads();   // also: all waves done reading x from bufA
  if (tid < 64){
    float s  = 0.f, ss = 0.f;
    #pragma unroll
    for (int i=0;i<8;++i){ s += red[tid*16 + i]; ss += red[tid*16 + 8 + i]; }
    float mu = s * (1.f/256.f);
    float var = ss * (1.f/256.f) - mu*mu;
    st[tid*2]   = mu;
    st[tid*2+1] = rsqrtf(var + 1e-5f);
  }
  __syncthreads();

  // LN + relu -> hr (f16) back into bufA
  #pragma unroll
  for (int mb=0;mb<4;++mb){
    #pragma unroll
    for (int r=0;r<4;++r){
      int row = mb*16 + hi4*4 + r;
      float mu = st[row*2], rs = st[row*2+1];
      #pragma unroll
      for (int nb=0;nb<2;++nb){
        int c = n0 + nb*16 + lo16;
        float v = (acc[mb][nb][r] - mu) * rs * g1v[nb] + bbv[nb];
        v = fmaxf(v, 0.f);
        int off = row*512 + (((c>>3) ^ (row&7))<<4) + (c&7)*2;
        *reinterpret_cast<f16_t*>(bufA + off) = (f16_t)v;
      }
    }
  }
  __syncthreads();

  // GEMM2: eo = hr @ W2[e]^T + b2
  #pragma unroll
  for (int mb=0;mb<4;++mb){
    #pragma unroll
    for (int nb=0;nb<2;++nb) acc[mb][nb] = (f32x4)0.0f;
  }
  if (W16) gemm_pipe(acc, bufA, src2, wt, lane, lo16, hi4);
  else     gemm_w32(acc, bufA, (const float*)W2v + e*65536, n0, lo16, hi4);

  // epilogue: eo store + scores partials (no bufA write, no barrier needed)
  #pragma unroll
  for (int mb=0;mb<4;++mb){
    #pragma unroll
    for (int r=0;r<4;++r){
      int row = mb*16 + hi4*4 + r;
      int b = b0 + row;
      float p0=0.f, p1=0.f, p2=0.f, p3=0.f;
      #pragma unroll
      for (int nb=0;nb<2;++nb){
        int c = n0 + nb*16 + lo16;
        float v = acc[mb][nb][r] + b2v[nb];
        eo_out[(b*256 + e)*256 + c] = v;
        f16x4 qk = *reinterpret_cast<const f16x4*>(qWkT + (b*256 + c)*4);
        p0 += v * (float)qk[0];
        p1 += v * (float)qk[1];
        p2 += v * (float)qk[2];
        p3 += v * (float)qk[3];
      }
      #pragma unroll
      for (int m=1;m<16;m<<=1){
        p0 += __shfl_xor(p0, m, 64); p1 += __shfl_xor(p1, m, 64);
        p2 += __shfl_xor(p2, m, 64); p3 += __shfl_xor(p3, m, 64);
      }
      if (lo16 == 0){
        red[row*32 + wid*4 + 0] = p0;
        red[row*32 + wid*4 + 1] = p1;
        red[row*32 + wid*4 + 2] = p2;
        red[row*32 + wid*4 + 3] = p3;
      }
    }
  }
  __syncthreads();
  if (tid < 256){
    int row = tid >> 2, n = tid & 3;
    float sc = 0.f;
    #pragma unroll
    for (int w=0;w<8;++w) sc += red[row*32 + w*4 + n];
    scores[((b0 + row)*4 + n)*256 + e] = sc + qbk[(b0 + row)*4 + n];
  }
}

// ---------------------------------------------------------------------------
// k_mini: out = act( maybeLN( (A @ W^T + bias) * scale ) ), 256x256x256, f16.
// grid 8 (32-row tiles), block 512 = 8 col-waves, acc[2][2].
// ---------------------------------------------------------------------------
__global__ __launch_bounds__(512, 4)
void k_mini(const float* __restrict__ A, const float* __restrict__ W,
            const float* __restrict__ bias, float scale, int do_ln,
            const float* __restrict__ g, const float* __restrict__ bb,
            int do_relu, float* __restrict__ out)
{
  __shared__ __align__(16) char lds[18688];
  char* bufA = lds;                    // 16KB: A rows (f16)
  float* red = (float*)(lds + 16384);  // [32][16] = 2KB
  float* st  = (float*)(lds + 18432);  // [32][2]  = 256B

  const int b0 = blockIdx.x * 32;
  const int tid = threadIdx.x;
  const int lane = tid & 63, wid = tid >> 6;
  const int lo16 = lane & 15, hi4 = lane >> 4;
  const int n0 = wid * 32;

  stage_f16<512>(A + b0*256, bufA, 32, tid);
  __syncthreads();

  f32x4 acc[2][2];
  #pragma unroll
  for (int mb=0;mb<2;++mb){
    #pragma unroll
    for (int nb=0;nb<2;++nb) acc[mb][nb] = (f32x4)0.0f;
  }
  #pragma unroll
  for (int kb = 0; kb < 8; ++kb){
    f16x8 bf[2];
    #pragma unroll
    for (int nb = 0; nb < 2; ++nb){
      const float4* p = reinterpret_cast<const float4*>(W + ((n0 + nb*16 + lo16)<<8) + kb*32 + hi4*8);
      bf[nb] = cvt8h(p[0], p[1]);
    }
    #pragma unroll
    for (int mb = 0; mb < 2; ++mb){
      f16x8 af = ldsA(bufA, mb*16 + lo16, kb*4 + hi4);
      acc[mb][0] = MFMA16(af, bf[0], acc[mb][0]);
      acc[mb][1] = MFMA16(af, bf[1], acc[mb][1]);
    }
  }

  float bv[2], gv[2], bbv[2];
  #pragma unroll
  for (int nb=0;nb<2;++nb){
    int c = n0 + nb*16 + lo16;
    bv[nb]  = bias[c];
    gv[nb]  = do_ln ? g[c]  : 1.f;
    bbv[nb] = do_ln ? bb[c] : 0.f;
  }
  #pragma unroll
  for (int mb=0;mb<2;++mb){
    #pragma unroll
    for (int nb=0;nb<2;++nb){
      #pragma unroll
      for (int r=0;r<4;++r) acc[mb][nb][r] = (acc[mb][nb][r] + bv[nb]) * scale;
    }
  }

  if (do_ln){
    #pragma unroll
    for (int mb=0;mb<2;++mb){
      #pragma unroll
      for (int r=0;r<4;++r){
        float s=0.f, ss=0.f;
        #pragma unroll
        for (int nb=0;nb<2;++nb){ float v = acc[mb][nb][r]; s += v; ss += v*v; }
        #pragma unroll
        for (int m=1;m<16;m<<=1){ s += __shfl_xor(s, m, 64); ss += __shfl_xor(ss, m, 64); }
        if (lo16 == 0){
          int row = mb*16 + hi4*4 + r;
          red[row*16 + wid]     = s;
          red[row*16 + 8 + wid] = ss;
        }
      }
    }
    __syncthreads();
    if (tid < 32){
      float s = 0.f, ss = 0.f;
      #pragma unroll
      for (int i=0;i<8;++i){ s += red[tid*16 + i]; ss += red[tid*16 + 8 + i]; }
      float mu = s * (1.f/256.f);
      float var = ss * (1.f/256.f) - mu*mu;
      st[tid*2]   = mu;
      st[tid*2+1] = rsqrtf(var + 1e-5f);
    }
    __syncthreads();
  }

  #pragma unroll
  for (int mb=0;mb<2;++mb){
    #pragma unroll
    for (int r=0;r<4;++r){
      int row = mb*16 + hi4*4 + r;
      float mu = 0.f, rs = 1.f;
      if (do_ln){ mu = st[row*2]; rs = st[row*2+1]; }
      #pragma unroll
      for (int nb=0;nb<2;++nb){
        int c = n0 + nb*16 + lo16;
        float v = acc[mb][nb][r];
        if (do_ln) v = (v - mu) * rs * gv[nb] + bbv[nb];
        if (do_relu) v = fmaxf(v, 0.f);
        out[(b0 + row)*256 + c] = v;
      }
    }
  }
}

// ---------------------------------------------------------------------------
__global__ __launch_bounds__(256)
void k3_softmax(const float* __restrict__ scores, float* __restrict__ wts)
{
  const int b = blockIdx.x, t = threadIdx.x;
  const int wid = t >> 6, lane = t & 63;
  __shared__ float r4[4];
  float sc[4];
  #pragma unroll
  for (int n=0;n<4;++n) sc[n] = scores[(b*4 + n)*256 + t];
  float wsum = 0.f;
  for (int n=0;n<4;++n){
    float m = sc[n];
    #pragma unroll
    for (int k=1;k<64;k<<=1) m = fmaxf(m, __shfl_xor(m, k, 64));
    if (lane == 0) r4[wid] = m;
    __syncthreads();
    m = fmaxf(fmaxf(r4[0], r4[1]), fmaxf(r4[2], r4[3]));
    __syncthreads();
    float ex = __expf(sc[n] - m);
    float s = ex;
    #pragma unroll
    for (int k=1;k<64;k<<=1) s += __shfl_xor(s, k, 64);
    if (lane == 0) r4[wid] = s;
    __syncthreads();
    s = r4[0] + r4[1] + r4[2] + r4[3];
    __syncthreads();
    wsum += ex / s;
  }
  wts[b*256 + t] = wsum * 0.25f;
}

// ---------------------------------------------------------------------------
// k4a: reference's literal einsum 'beh,eh->bh' with weights shape (B,E):
//   combined[b,h] = sum_e eo[b,e,h] * wts_flat[e*256 + h]
// ---------------------------------------------------------------------------
__global__ __launch_bounds__(1024)
void k4a_combined(const float* __restrict__ eo, const float* __restrict__ wts,
                  float* __restrict__ cmb)
{
  __shared__ float part[1024];
  const int b = blockIdx.x, t = threadIdx.x;
  const int c = t >> 8, h = t & 255;
  const float* p = eo + b*65536 + h;
  float s = 0.f;
  #pragma unroll 8
  for (int i = 0; i < 64; ++i){
    int e2 = c*64 + i;
    s += p[e2*256] * wts[e2*256 + h];
  }
  part[t] = s;
  __syncthreads();
  if (t < 256) cmb[b*256 + t] = part[t] + part[t+256] + part[t+512] + part[t+768];
}

extern "C" void kernel_launch(void* const* d_in, const int* in_sizes, int n_in,
                              void* d_out, int out_size, void* d_ws, size_t ws_size,
                              hipStream_t stream)
{
  const float* x    = (const float*)d_in[0];
  const float* te   = (const float*)d_in[1];
  const float* W1   = (const float*)d_in[2];
  const float* b1   = (const float*)d_in[3];
  const float* g1   = (const float*)d_in[4];
  const float* bb1  = (const float*)d_in[5];
  const float* W2   = (const float*)d_in[6];
  const float* b2   = (const float*)d_in[7];
  const float* ipw  = (const float*)d_in[8];
  const float* ipb  = (const float*)d_in[9];
  const float* cw   = (const float*)d_in[10];
  const float* cb   = (const float*)d_in[11];
  const float* cg   = (const float*)d_in[12];
  const float* cbt  = (const float*)d_in[13];

  float* out    = (float*)d_out;        // (256,256)
  float* wts    = out + 65536;          // (256,1,256)
  float* eo     = out + 131072;         // (256,256,256)

  // ws layout: [w1h 32MB | w2h 32MB] | regA 1MB | qWkT 512KB | qbk 4KB
  const size_t F16_BYTES = 2ull * 16777216ull * 2;                 // 67,108,864
  const size_t NEED = F16_BYTES + 1048576 + 524288 + 4096;         // 68,685,824
  const bool f16w = ws_size >= NEED;

  f16_t* w1h = (f16_t*)d_ws;
  f16_t* w2h = w1h + 16777216;
  char* tail = f16w ? ((char*)d_ws + F16_BYTES) : (char*)d_ws;
  float* regA  = (float*)tail;                       // 262144 f32
  f16_t* qwkt  = (f16_t*)(tail + 1048576);           // 262144 f16
  float* qbk   = (float*)(tail + 1048576 + 524288);  // 1024 f32
  float* q      = regA;
  float* scores = regA;
  float* cmb    = regA;

  // q = (te @ Wq^T + bq) / 8
  k_mini<<<8, 512, 0, stream>>>(te, ipw, ipb, 0.125f, 0, nullptr, nullptr, 0, q);
  // fold q into Wk via MFMA micro-kernel: qWkT[b,h,:] and qbk[b,:]
  kqwk2<<<16, 256, 0, stream>>>(q, ipw + 65536, ipb, qwkt, qbk);

  if (f16w){
    k0_cvt<<<2048, 256, 0, stream>>>(W1, W2, w1h, w2h);
    k2_fused<1><<<1024, 512, 0, stream>>>(x, w1h, b1, g1, bb1, w2h, b2,
                                          qwkt, qbk, eo, scores);
  } else {
    k2_fused<0><<<1024, 512, 0, stream>>>(x, W1, b1, g1, bb1, W2, b2,
                                          qwkt, qbk, eo, scores);
  }

  // softmax over experts, mean over heads -> weights (out)
  k3_softmax<<<256, 256, 0, stream>>>(scores, wts);
  // combined[b,h] = sum_e eo[b,e,h] * wts[e,h]
  k4a_combined<<<256, 1024, 0, stream>>>(eo, wts, cmb);
  // out = relu(LN(combined @ cw^T + cb))
  k_mini<<<8, 512, 0, stream>>>(cmb, cw, cb, 1.0f, 1, cg, cbt, 1, out);
}

// Round 15
// 147.722 us; speedup vs baseline: 1.0386x; 1.0237x over previous
//
#include <hip/hip_runtime.h>

typedef _Float16 f16_t;
typedef f16_t f16x8 __attribute__((ext_vector_type(8)));
typedef f16_t f16x4 __attribute__((ext_vector_type(4)));
typedef float f32x4 __attribute__((ext_vector_type(4)));

#define MFMA16(a,b,c) __builtin_amdgcn_mfma_f32_16x16x32_f16(a,b,c,0,0,0)
#define VM0 asm volatile("s_waitcnt vmcnt(0)" ::: "memory")
#define VM2 asm volatile("s_waitcnt vmcnt(2)" ::: "memory")

// async global -> LDS, 16B per lane (dest = wave-uniform base + lane*16).
__device__ __forceinline__ void cp16(const void* g, void* l){
  __builtin_amdgcn_global_load_lds(
      (const __attribute__((address_space(1))) void*)g,
      (__attribute__((address_space(3))) void*)l, 16, 0, 0);
}

__device__ __forceinline__ f16x8 cvt8h(float4 a, float4 b){
  f16x8 r;
  r[0]=(f16_t)a.x; r[1]=(f16_t)a.y; r[2]=(f16_t)a.z; r[3]=(f16_t)a.w;
  r[4]=(f16_t)b.x; r[5]=(f16_t)b.y; r[6]=(f16_t)b.z; r[7]=(f16_t)b.w;
  return r;
}

// Stage rows x 256 f32 (row-major) -> LDS f16 [row][256], per-row XOR swizzle
// on 16B chunks: chunk' = chunk ^ (row&7). Row pitch 512B.
template<int NT>
__device__ __forceinline__ void stage_f16(const float* __restrict__ src,
                                          char* dst, int rows, int tid){
  const int nchunk = rows * 32;
  const float4* s4 = reinterpret_cast<const float4*>(src);
  for (int cid = tid; cid < nchunk; cid += NT){
    int r = cid >> 5, c = cid & 31;
    *reinterpret_cast<f16x8*>(dst + r*512 + ((c ^ (r&7))<<4)) = cvt8h(s4[cid*2], s4[cid*2+1]);
  }
}

__device__ __forceinline__ f16x8 ldsA(const char* buf, int row, int c16){
  return *reinterpret_cast<const f16x8*>(buf + row*512 + ((c16 ^ (row&7))<<4));
}

// ---- wave-private W pipeline (ROUND-8 configuration, the best-known one) ---
// Lane l loads W[(n0 + (l>>2))*256 + kb*32 + (l&3)*8] into linear LDS slot
// l*16. B-fragment read: region nb*1024 + lo16*64 + hi4*16.
__device__ __forceinline__ void issue_tile(const f16_t* wsrc_lane, int kb, char* wt, int lane){
  const f16_t* s = wsrc_lane + kb*32;
  char* d = wt + (kb&1)*2048 + lane*16;
  cp16(s, d);
  cp16(s + 16*256, d + 1024);
}

// 64x32 C tile, K=256, software-pipelined: consume tile kb (vmcnt(2): tile
// kb+1 stays in flight), then issue tile kb+2 into the slot kb just freed.
// NO setprio (m190 + r11's +6-8us regression in this lockstep structure).
__device__ __forceinline__ void gemm_pipe(f32x4 acc[4][2], const char* bufA,
    const f16_t* wsrc_lane, char* wt, int lane, int lo16, int hi4){
  #pragma unroll
  for (int kb = 0; kb < 8; ++kb){
    if (kb < 7) { VM2; } else { VM0; }
    const char* ws = wt + (kb&1)*2048 + lo16*64 + hi4*16;
    f16x8 bf0 = *reinterpret_cast<const f16x8*>(ws);
    f16x8 bf1 = *reinterpret_cast<const f16x8*>(ws + 1024);
    #pragma unroll
    for (int mb = 0; mb < 4; ++mb){
      f16x8 af = ldsA(bufA, mb*16 + lo16, kb*4 + hi4);
      acc[mb][0] = MFMA16(af, bf0, acc[mb][0]);
      acc[mb][1] = MFMA16(af, bf1, acc[mb][1]);
    }
    __builtin_amdgcn_sched_barrier(0);   // keep the refill below the reads above
    if (kb + 2 < 8) issue_tile(wsrc_lane, kb + 2, wt, lane);
  }
}

// f32-W streaming fallback (only used when ws_size can't hold f16 weights)
__device__ __forceinline__ void gemm_w32(f32x4 acc[4][2], const char* bufA,
    const float* __restrict__ W, int n0, int lo16, int hi4){
  #pragma unroll
  for (int kb = 0; kb < 8; ++kb){
    f16x8 bf[2];
    #pragma unroll
    for (int nb = 0; nb < 2; ++nb){
      const float4* p = reinterpret_cast<const float4*>(W + ((n0 + nb*16 + lo16)<<8) + kb*32 + hi4*8);
      bf[nb] = cvt8h(p[0], p[1]);
    }
    #pragma unroll
    for (int mb = 0; mb < 4; ++mb){
      f16x8 af = ldsA(bufA, mb*16 + lo16, kb*4 + hi4);
      acc[mb][0] = MFMA16(af, bf[0], acc[mb][0]);
      acc[mb][1] = MFMA16(af, bf[1], acc[mb][1]);
    }
  }
}

// ---------------------------------------------------------------------------
// k0_cvt: one-shot f32 -> f16 conversion of W1, W2 into d_ws. BW-roofline
// (192MB ~= 20-25us); r10 proved eliminating it costs more in k2.
// ---------------------------------------------------------------------------
__global__ __launch_bounds__(256)
void k0_cvt(const float* __restrict__ W1, const float* __restrict__ W2,
            f16_t* __restrict__ w1h, f16_t* __restrict__ w2h)
{
  const long long NG1 = 2097152, NGT = 4194304; // 8-elem groups
  for (long long gidx = (long long)blockIdx.x*256 + threadIdx.x; gidx < NGT;
       gidx += (long long)gridDim.x*256){
    const float4* s; f16_t* d; long long off;
    if (gidx < NG1){ s = (const float4*)W1; d = w1h; off = gidx; }
    else { s = (const float4*)W2; d = w2h; off = gidx - NG1; }
    *reinterpret_cast<f16x8*>(d + off*8) = cvt8h(s[off*2], s[off*2+1]);
  }
}

// ---------------------------------------------------------------------------
// kqwk2: per (n, h-chunk) MFMA micro-kernel:
//   qWkT[b][h][n] = sum_d q[b, n*64+d] * Wk[n*64+d, h]
//   qbk[b][n]     = sum_d q[b, n*64+d] * bk[n*64+d]       (hc==0 blocks)
// ---------------------------------------------------------------------------
__global__ __launch_bounds__(256)
void kqwk2(const float* __restrict__ q, const float* __restrict__ Wk,
           const float* __restrict__ ipb, f16_t* __restrict__ qWkT,
           float* __restrict__ qbk)
{
  __shared__ __align__(16) char lds[41216];
  char* qA   = lds;                       // [256][64] f16, pitch 128B, swizzled
  char* wkT  = lds + 32768;               // [64 h][64 d] f16, pitch 128B, swizzled
  float* sipb = (float*)(lds + 40960);    // [64]

  const int bx = blockIdx.x;
  const int n  = bx >> 2, hc = bx & 3;
  const int t  = threadIdx.x;
  const int lane = t & 63, wid = t >> 6;
  const int lo16 = lane & 15, hi4 = lane >> 4;
  const int m0 = wid * 64;

  {
    const float4* s4 = reinterpret_cast<const float4*>(q);
    for (int cid = t; cid < 2048; cid += 256){
      int b = cid >> 3, c = cid & 7;
      int si = b*64 + n*16 + c*2;
      *reinterpret_cast<f16x8*>(qA + b*128 + ((c ^ (b&7))<<4)) = cvt8h(s4[si], s4[si+1]);
    }
  }
  for (int idx = t; idx < 4096; idx += 256){
    int d = idx >> 6, hh = idx & 63;
    float v = Wk[(n*64 + d)*256 + hc*64 + hh];
    *reinterpret_cast<f16_t*>(wkT + hh*128 + (((d>>3) ^ (hh&7))<<4) + (d&7)*2) = (f16_t)v;
  }
  if (hc == 0 && t < 64) sipb[t] = ipb[256 + n*64 + t];
  __syncthreads();

  f32x4 acc[4][4];
  #pragma unroll
  for (int mb=0;mb<4;++mb){
    #pragma unroll
    for (int nb=0;nb<4;++nb) acc[mb][nb] = (f32x4)0.0f;
  }

  #pragma unroll
  for (int kb = 0; kb < 2; ++kb){
    int c16 = kb*4 + hi4;
    f16x8 bf[4], af[4];
    #pragma unroll
    for (int nb = 0; nb < 4; ++nb){
      int h = nb*16 + lo16;
      bf[nb] = *reinterpret_cast<const f16x8*>(wkT + h*128 + ((c16 ^ (h&7))<<4));
    }
    #pragma unroll
    for (int mb = 0; mb < 4; ++mb){
      int row = m0 + mb*16 + lo16;
      af[mb] = *reinterpret_cast<const f16x8*>(qA + row*128 + ((c16 ^ (row&7))<<4));
    }
    #pragma unroll
    for (int mb = 0; mb < 4; ++mb){
      #pragma unroll
      for (int nb = 0; nb < 4; ++nb) acc[mb][nb] = MFMA16(af[mb], bf[nb], acc[mb][nb]);
    }
  }

  #pragma unroll
  for (int mb=0;mb<4;++mb){
    #pragma unroll
    for (int r=0;r<4;++r){
      int b = m0 + mb*16 + hi4*4 + r;
      #pragma unroll
      for (int nb=0;nb<4;++nb){
        int h = hc*64 + nb*16 + lo16;
        qWkT[(b*256 + h)*4 + n] = (f16_t)acc[mb][nb][r];
      }
    }
  }

  if (hc == 0){
    int b = t;
    float s = 0.f;
    #pragma unroll 8
    for (int d = 0; d < 64; ++d){
      f16_t qv = *reinterpret_cast<const f16_t*>(qA + b*128 + (((d>>3) ^ (b&7))<<4) + (d&7)*2);
      s += (float)qv * sipb[d];
    }
    qbk[b*4 + n] = s;
  }
}

// ---------------------------------------------------------------------------
// k2_fused: per (expert e, 64-row batch tile):
//   h = x@W1[e]^T + b1 ; LN ; relu -> hr(f16 LDS) ; eo = hr@W2[e]^T + b2 ->
//   global f32 ; scores partials via qWkT dot (GEMM3 eliminated).
// grid 1024 XCD-swizzled; block 512 = 8 col-waves. Round-8 pipe (no setprio,
// lane>>2 permutation). LDS 74.2KB -> 2 blocks/CU. FROZEN (best-known).
// ---------------------------------------------------------------------------
template<int W16>
__global__ __launch_bounds__(512, 4)
void k2_fused(const float* __restrict__ x, const void* __restrict__ W1v,
              const float* __restrict__ b1, const float* __restrict__ g1,
              const float* __restrict__ bb1, const void* __restrict__ W2v,
              const float* __restrict__ b2, const f16_t* __restrict__ qWkT,
              const float* __restrict__ qbk,
              float* __restrict__ eo_out, float* __restrict__ scores)
{
  __shared__ __align__(16) char lds[74240];
  char* bufA = lds;                    // 32KB: x(f16) -> hr(f16)
  float* red = (float*)(lds + 32768);  // 8KB: LN [64][16] / scores [64][8][4]
  float* st  = (float*)(lds + 40960);  // [64][2] = 512B
  char* wpipe = lds + 41472;           // 8 waves x 2 slots x 2KB = 32KB

  const int l = blockIdx.x;
  const int e    = (l & 7) * 32 + (l >> 5);
  const int b0   = ((l >> 3) & 3) * 64;
  const int tid = threadIdx.x;
  const int lane = tid & 63, wid = tid >> 6;
  const int lo16 = lane & 15, hi4 = lane >> 4;
  const int n0 = wid * 32;
  char* wt = wpipe + wid*4096;

  const int pl = (n0 + (lane >> 2))*256 + (lane & 3)*8;
  const f16_t* src1 = nullptr; const f16_t* src2 = nullptr;
  if (W16){
    src1 = (const f16_t*)W1v + e*65536 + pl;
    src2 = (const f16_t*)W2v + e*65536 + pl;
    issue_tile(src1, 0, wt, lane);       // G1 prefetch hides under x-stage
    issue_tile(src1, 1, wt, lane);
  }

  stage_f16<512>(x + b0*256, bufA, 64, tid);
  __syncthreads();

  f32x4 acc[4][2];
  #pragma unroll
  for (int mb=0;mb<4;++mb){
    #pragma unroll
    for (int nb=0;nb<2;++nb) acc[mb][nb] = (f32x4)0.0f;
  }

  if (W16) gemm_pipe(acc, bufA, src1, wt, lane, lo16, hi4);
  else     gemm_w32(acc, bufA, (const float*)W1v + e*65536, n0, lo16, hi4);

  if (W16){                              // G2 prefetch hides under LN phase
    issue_tile(src2, 0, wt, lane);
    issue_tile(src2, 1, wt, lane);
  }

  float b1v[2], g1v[2], bbv[2], b2v[2];
  #pragma unroll
  for (int nb=0;nb<2;++nb){
    int c = n0 + nb*16 + lo16;
    b1v[nb] = b1[e*256 + c];
    g1v[nb] = g1[e*256 + c];
    bbv[nb] = bb1[e*256 + c];
    b2v[nb] = b2[e*256 + c];
  }
  #pragma unroll
  for (int mb=0;mb<4;++mb){
    #pragma unroll
    for (int nb=0;nb<2;++nb){
      #pragma unroll
      for (int r=0;r<4;++r) acc[mb][nb][r] += b1v[nb];
    }
  }

  // LN stats: per-row sum/sumsq across the 8 column-waves
  #pragma unroll
  for (int mb=0;mb<4;++mb){
    #pragma unroll
    for (int r=0;r<4;++r){
      float s=0.f, ss=0.f;
      #pragma unroll
      for (int nb=0;nb<2;++nb){ float v = acc[mb][nb][r]; s += v; ss += v*v; }
      #pragma unroll
      for (int m=1;m<16;m<<=1){ s += __shfl_xor(s, m, 64); ss += __shfl_xor(ss, m, 64); }
      if (lo16 == 0){
        int row = mb*16 + hi4*4 + r;
        red[row*16 + wid]     = s;
        red[row*16 + 8 + wid] = ss;
      }
    }
  }
  __syncthreads();   // also: all waves done reading x from bufA
  if (tid < 64){
    float s  = 0.f, ss = 0.f;
    #pragma unroll
    for (int i=0;i<8;++i){ s += red[tid*16 + i]; ss += red[tid*16 + 8 + i]; }
    float mu = s * (1.f/256.f);
    float var = ss * (1.f/256.f) - mu*mu;
    st[tid*2]   = mu;
    st[tid*2+1] = rsqrtf(var + 1e-5f);
  }
  __syncthreads();

  // LN + relu -> hr (f16) back into bufA
  #pragma unroll
  for (int mb=0;mb<4;++mb){
    #pragma unroll
    for (int r=0;r<4;++r){
      int row = mb*16 + hi4*4 + r;
      float mu = st[row*2], rs = st[row*2+1];
      #pragma unroll
      for (int nb=0;nb<2;++nb){
        int c = n0 + nb*16 + lo16;
        float v = (acc[mb][nb][r] - mu) * rs * g1v[nb] + bbv[nb];
        v = fmaxf(v, 0.f);
        int off = row*512 + (((c>>3) ^ (row&7))<<4) + (c&7)*2;
        *reinterpret_cast<f16_t*>(bufA + off) = (f16_t)v;
      }
    }
  }
  __syncthreads();

  // GEMM2: eo = hr @ W2[e]^T + b2
  #pragma unroll
  for (int mb=0;mb<4;++mb){
    #pragma unroll
    for (int nb=0;nb<2;++nb) acc[mb][nb] = (f32x4)0.0f;
  }
  if (W16) gemm_pipe(acc, bufA, src2, wt, lane, lo16, hi4);
  else     gemm_w32(acc, bufA, (const float*)W2v + e*65536, n0, lo16, hi4);

  // epilogue: eo store + scores partials
  #pragma unroll
  for (int mb=0;mb<4;++mb){
    #pragma unroll
    for (int r=0;r<4;++r){
      int row = mb*16 + hi4*4 + r;
      int b = b0 + row;
      float p0=0.f, p1=0.f, p2=0.f, p3=0.f;
      #pragma unroll
      for (int nb=0;nb<2;++nb){
        int c = n0 + nb*16 + lo16;
        float v = acc[mb][nb][r] + b2v[nb];
        eo_out[(b*256 + e)*256 + c] = v;
        f16x4 qk = *reinterpret_cast<const f16x4*>(qWkT + (b*256 + c)*4);
        p0 += v * (float)qk[0];
        p1 += v * (float)qk[1];
        p2 += v * (float)qk[2];
        p3 += v * (float)qk[3];
      }
      #pragma unroll
      for (int m=1;m<16;m<<=1){
        p0 += __shfl_xor(p0, m, 64); p1 += __shfl_xor(p1, m, 64);
        p2 += __shfl_xor(p2, m, 64); p3 += __shfl_xor(p3, m, 64);
      }
      if (lo16 == 0){
        red[row*32 + wid*4 + 0] = p0;
        red[row*32 + wid*4 + 1] = p1;
        red[row*32 + wid*4 + 2] = p2;
        red[row*32 + wid*4 + 3] = p3;
      }
    }
  }
  __syncthreads();
  if (tid < 256){
    int row = tid >> 2, n = tid & 3;
    float sc = 0.f;
    #pragma unroll
    for (int w=0;w<8;++w) sc += red[row*32 + w*4 + n];
    scores[((b0 + row)*4 + n)*256 + e] = sc + qbk[(b0 + row)*4 + n];
  }
}

// ---------------------------------------------------------------------------
// k_mini: out = (A @ W^T + bias) * scale, 256x256x256, f16. (q-projection)
// ---------------------------------------------------------------------------
__global__ __launch_bounds__(512, 4)
void k_mini(const float* __restrict__ A, const float* __restrict__ W,
            const float* __restrict__ bias, float scale,
            float* __restrict__ out)
{
  __shared__ __align__(16) char lds[16384];
  char* bufA = lds;                    // 16KB: A rows (f16)

  const int b0 = blockIdx.x * 32;
  const int tid = threadIdx.x;
  const int lane = tid & 63, wid = tid >> 6;
  const int lo16 = lane & 15, hi4 = lane >> 4;
  const int n0 = wid * 32;

  stage_f16<512>(A + b0*256, bufA, 32, tid);
  __syncthreads();

  f32x4 acc[2][2];
  #pragma unroll
  for (int mb=0;mb<2;++mb){
    #pragma unroll
    for (int nb=0;nb<2;++nb) acc[mb][nb] = (f32x4)0.0f;
  }
  #pragma unroll
  for (int kb = 0; kb < 8; ++kb){
    f16x8 bf[2];
    #pragma unroll
    for (int nb = 0; nb < 2; ++nb){
      const float4* p = reinterpret_cast<const float4*>(W + ((n0 + nb*16 + lo16)<<8) + kb*32 + hi4*8);
      bf[nb] = cvt8h(p[0], p[1]);
    }
    #pragma unroll
    for (int mb = 0; mb < 2; ++mb){
      f16x8 af = ldsA(bufA, mb*16 + lo16, kb*4 + hi4);
      acc[mb][0] = MFMA16(af, bf[0], acc[mb][0]);
      acc[mb][1] = MFMA16(af, bf[1], acc[mb][1]);
    }
  }

  float bv[2];
  #pragma unroll
  for (int nb=0;nb<2;++nb) bv[nb] = bias[n0 + nb*16 + lo16];

  #pragma unroll
  for (int mb=0;mb<2;++mb){
    #pragma unroll
    for (int r=0;r<4;++r){
      int row = mb*16 + hi4*4 + r;
      #pragma unroll
      for (int nb=0;nb<2;++nb){
        int c = n0 + nb*16 + lo16;
        out[(b0 + row)*256 + c] = (acc[mb][nb][r] + bv[nb]) * scale;
      }
    }
  }
}

// ---------------------------------------------------------------------------
__global__ __launch_bounds__(256)
void k3_softmax(const float* __restrict__ scores, float* __restrict__ wts)
{
  const int b = blockIdx.x, t = threadIdx.x;
  const int wid = t >> 6, lane = t & 63;
  __shared__ float r4[4];
  float sc[4];
  #pragma unroll
  for (int n=0;n<4;++n) sc[n] = scores[(b*4 + n)*256 + t];
  float wsum = 0.f;
  for (int n=0;n<4;++n){
    float m = sc[n];
    #pragma unroll
    for (int k=1;k<64;k<<=1) m = fmaxf(m, __shfl_xor(m, k, 64));
    if (lane == 0) r4[wid] = m;
    __syncthreads();
    m = fmaxf(fmaxf(r4[0], r4[1]), fmaxf(r4[2], r4[3]));
    __syncthreads();
    float ex = __expf(sc[n] - m);
    float s = ex;
    #pragma unroll
    for (int k=1;k<64;k<<=1) s += __shfl_xor(s, k, 64);
    if (lane == 0) r4[wid] = s;
    __syncthreads();
    s = r4[0] + r4[1] + r4[2] + r4[3];
    __syncthreads();
    wsum += ex / s;
  }
  wts[b*256 + t] = wsum * 0.25f;
}

// ---------------------------------------------------------------------------
// kB: fused k4a + final projection + LN + relu. Per block b:
//   cmb[k] = sum_e eo[b,e,k] * wts_flat[e*256+k]     (reference's literal einsum)
//   y[h]   = sum_k cmb[k] * cw[h,k] + cb[h]
//   out[b,h] = relu((y - mu)*rsqrt(var+eps)*cg + cbt)
// grid 256, block 1024 (4-way e-split / 4-way k-split). Removes the cmb
// HBM round-trip and one kernel launch; final math in f32 (more accurate).
// ---------------------------------------------------------------------------
__global__ __launch_bounds__(1024)
void kB_out(const float* __restrict__ eo, const float* __restrict__ wts,
            const float* __restrict__ cw, const float* __restrict__ cb,
            const float* __restrict__ cg, const float* __restrict__ cbt,
            float* __restrict__ out)
{
  __shared__ float part[1024];
  __shared__ float cmb_l[256];
  __shared__ float vl[256];
  __shared__ float st2[2];
  const int b = blockIdx.x, t = threadIdx.x;
  const int c = t >> 8, h = t & 255;

  // phase 1: combined (4-way e-split, coalesced over h)
  {
    const float* p = eo + b*65536 + h;
    float s = 0.f;
    #pragma unroll 8
    for (int i = 0; i < 64; ++i){
      int e2 = c*64 + i;
      s += p[e2*256] * wts[e2*256 + h];
    }
    part[t] = s;
  }
  __syncthreads();
  if (t < 256) cmb_l[t] = part[t] + part[t+256] + part[t+512] + part[t+768];
  __syncthreads();

  // phase 2: y[h] partial over k in [c*64, c*64+64)
  {
    const float* cwr = cw + h*256 + c*64;
    float y = 0.f;
    #pragma unroll 8
    for (int k = 0; k < 64; ++k) y += cmb_l[c*64 + k] * cwr[k];
    part[t] = y;
  }
  __syncthreads();
  if (t < 256) vl[t] = part[t] + part[t+256] + part[t+512] + part[t+768] + cb[t];
  __syncthreads();

  // LN stats over the 256 values (one wave)
  if (t < 64){
    float s = 0.f, ss = 0.f;
    #pragma unroll
    for (int i = 0; i < 4; ++i){
      float v = vl[t*4 + i];
      s += v; ss += v*v;
    }
    #pragma unroll
    for (int m=1;m<64;m<<=1){ s += __shfl_xor(s, m, 64); ss += __shfl_xor(ss, m, 64); }
    if (t == 0){
      float mu = s * (1.f/256.f);
      float var = ss * (1.f/256.f) - mu*mu;
      st2[0] = mu;
      st2[1] = rsqrtf(var + 1e-5f);
    }
  }
  __syncthreads();

  if (t < 256){
    float v = (vl[t] - st2[0]) * st2[1] * cg[t] + cbt[t];
    out[b*256 + t] = fmaxf(v, 0.f);
  }
}

extern "C" void kernel_launch(void* const* d_in, const int* in_sizes, int n_in,
                              void* d_out, int out_size, void* d_ws, size_t ws_size,
                              hipStream_t stream)
{
  const float* x    = (const float*)d_in[0];
  const float* te   = (const float*)d_in[1];
  const float* W1   = (const float*)d_in[2];
  const float* b1   = (const float*)d_in[3];
  const float* g1   = (const float*)d_in[4];
  const float* bb1  = (const float*)d_in[5];
  const float* W2   = (const float*)d_in[6];
  const float* b2   = (const float*)d_in[7];
  const float* ipw  = (const float*)d_in[8];
  const float* ipb  = (const float*)d_in[9];
  const float* cw   = (const float*)d_in[10];
  const float* cb   = (const float*)d_in[11];
  const float* cg   = (const float*)d_in[12];
  const float* cbt  = (const float*)d_in[13];

  float* out    = (float*)d_out;        // (256,256)
  float* wts    = out + 65536;          // (256,1,256)
  float* eo     = out + 131072;         // (256,256,256)

  // ws layout: [w1h 32MB | w2h 32MB] | regA 1MB | qWkT 512KB | qbk 4KB
  const size_t F16_BYTES = 2ull * 16777216ull * 2;                 // 67,108,864
  const size_t NEED = F16_BYTES + 1048576 + 524288 + 4096;         // 68,685,824
  const bool f16w = ws_size >= NEED;

  f16_t* w1h = (f16_t*)d_ws;
  f16_t* w2h = w1h + 16777216;
  char* tail = f16w ? ((char*)d_ws + F16_BYTES) : (char*)d_ws;
  float* regA  = (float*)tail;                       // 262144 f32
  f16_t* qwkt  = (f16_t*)(tail + 1048576);           // 262144 f16
  float* qbk   = (float*)(tail + 1048576 + 524288);  // 1024 f32
  float* q      = regA;
  float* scores = regA;

  // q = (te @ Wq^T + bq) / 8
  k_mini<<<8, 512, 0, stream>>>(te, ipw, ipb, 0.125f, q);
  // fold q into Wk via MFMA micro-kernel: qWkT[b,h,:] and qbk[b,:]
  kqwk2<<<16, 256, 0, stream>>>(q, ipw + 65536, ipb, qwkt, qbk);

  if (f16w){
    k0_cvt<<<2048, 256, 0, stream>>>(W1, W2, w1h, w2h);
    k2_fused<1><<<1024, 512, 0, stream>>>(x, w1h, b1, g1, bb1, w2h, b2,
                                          qwkt, qbk, eo, scores);
  } else {
    k2_fused<0><<<1024, 512, 0, stream>>>(x, W1, b1, g1, bb1, W2, b2,
                                          qwkt, qbk, eo, scores);
  }

  // softmax over experts, mean over heads -> weights (out)
  k3_softmax<<<256, 256, 0, stream>>>(scores, wts);
  // combined + final projection + LN + relu, fused
  kB_out<<<256, 1024, 0, stream>>>(eo, wts, cw, cb, cg, cbt, out);
}

// Round 16
// 141.671 us; speedup vs baseline: 1.0829x; 1.0427x over previous
//
#include <hip/hip_runtime.h>

typedef _Float16 f16_t;
typedef f16_t f16x8 __attribute__((ext_vector_type(8)));
typedef float f32x4 __attribute__((ext_vector_type(4)));

#define MFMA16(a,b,c) __builtin_amdgcn_mfma_f32_16x16x32_f16(a,b,c,0,0,0)
#define VM0 asm volatile("s_waitcnt vmcnt(0)" ::: "memory")
#define VM2 asm volatile("s_waitcnt vmcnt(2)" ::: "memory")

// async global -> LDS, 16B per lane (dest = wave-uniform base + lane*16).
__device__ __forceinline__ void cp16(const void* g, void* l){
  __builtin_amdgcn_global_load_lds(
      (const __attribute__((address_space(1))) void*)g,
      (__attribute__((address_space(3))) void*)l, 16, 0, 0);
}

__device__ __forceinline__ f16x8 cvt8h(float4 a, float4 b){
  f16x8 r;
  r[0]=(f16_t)a.x; r[1]=(f16_t)a.y; r[2]=(f16_t)a.z; r[3]=(f16_t)a.w;
  r[4]=(f16_t)b.x; r[5]=(f16_t)b.y; r[6]=(f16_t)b.z; r[7]=(f16_t)b.w;
  return r;
}

// Stage rows x 256 f32 (row-major) -> LDS f16 [row][256], per-row XOR swizzle
// on 16B chunks: chunk' = chunk ^ (row&7). Row pitch 512B.
template<int NT>
__device__ __forceinline__ void stage_f16(const float* __restrict__ src,
                                          char* dst, int rows, int tid){
  const int nchunk = rows * 32;
  const float4* s4 = reinterpret_cast<const float4*>(src);
  for (int cid = tid; cid < nchunk; cid += NT){
    int r = cid >> 5, c = cid & 31;
    *reinterpret_cast<f16x8*>(dst + r*512 + ((c ^ (r&7))<<4)) = cvt8h(s4[cid*2], s4[cid*2+1]);
  }
}

__device__ __forceinline__ f16x8 ldsA(const char* buf, int row, int c16){
  return *reinterpret_cast<const f16x8*>(buf + row*512 + ((c16 ^ (row&7))<<4));
}

// ---- wave-private W pipeline (ROUND-8 exact: the measured-84.6us config) ---
// Lane l loads W[(n0 + (l>>2))*256 + kb*32 + (l&3)*8] into linear LDS slot
// l*16. B-fragment read: region nb*1024 + lo16*64 + hi4*16.
__device__ __forceinline__ void issue_tile(const f16_t* wsrc_lane, int kb, char* wt, int lane){
  const f16_t* s = wsrc_lane + kb*32;
  char* d = wt + (kb&1)*2048 + lane*16;
  cp16(s, d);
  cp16(s + 16*256, d + 1024);
}

// 64x32 C tile, K=256, software-pipelined: consume tile kb (vmcnt(2): tile
// kb+1 stays in flight), then issue tile kb+2 into the slot kb just freed.
// No setprio (m190 + r11 regression evidence in this lockstep structure).
__device__ __forceinline__ void gemm_pipe(f32x4 acc[4][2], const char* bufA,
    const f16_t* wsrc_lane, char* wt, int lane, int lo16, int hi4){
  #pragma unroll
  for (int kb = 0; kb < 8; ++kb){
    if (kb < 7) { VM2; } else { VM0; }
    const char* ws = wt + (kb&1)*2048 + lo16*64 + hi4*16;
    f16x8 bf0 = *reinterpret_cast<const f16x8*>(ws);
    f16x8 bf1 = *reinterpret_cast<const f16x8*>(ws + 1024);
    #pragma unroll
    for (int mb = 0; mb < 4; ++mb){
      f16x8 af = ldsA(bufA, mb*16 + lo16, kb*4 + hi4);
      acc[mb][0] = MFMA16(af, bf0, acc[mb][0]);
      acc[mb][1] = MFMA16(af, bf1, acc[mb][1]);
    }
    __builtin_amdgcn_sched_barrier(0);   // keep the refill below the reads above
    if (kb + 2 < 8) issue_tile(wsrc_lane, kb + 2, wt, lane);
  }
}

// f32-W streaming fallback (only used when ws_size can't hold f16 weights)
__device__ __forceinline__ void gemm_w32(f32x4 acc[4][2], const char* bufA,
    const float* __restrict__ W, int n0, int lo16, int hi4){
  #pragma unroll
  for (int kb = 0; kb < 8; ++kb){
    f16x8 bf[2];
    #pragma unroll
    for (int nb = 0; nb < 2; ++nb){
      const float4* p = reinterpret_cast<const float4*>(W + ((n0 + nb*16 + lo16)<<8) + kb*32 + hi4*8);
      bf[nb] = cvt8h(p[0], p[1]);
    }
    #pragma unroll
    for (int mb = 0; mb < 4; ++mb){
      f16x8 af = ldsA(bufA, mb*16 + lo16, kb*4 + hi4);
      acc[mb][0] = MFMA16(af, bf[0], acc[mb][0]);
      acc[mb][1] = MFMA16(af, bf[1], acc[mb][1]);
    }
  }
}

// ---------------------------------------------------------------------------
// k0_cvt: one-shot f32 -> f16 conversion of W1, W2, Wk into d_ws.
// BW-roofline (~194MB); r10 proved eliminating it costs more in k2.
// ---------------------------------------------------------------------------
__global__ __launch_bounds__(256)
void k0_cvt(const float* __restrict__ W1, const float* __restrict__ W2,
            const float* __restrict__ Wk, f16_t* __restrict__ w1h,
            f16_t* __restrict__ w2h, f16_t* __restrict__ wkh)
{
  const long long NG1 = 2097152, NG2 = 4194304, NGT = 4202496; // 8-elem groups
  for (long long gidx = (long long)blockIdx.x*256 + threadIdx.x; gidx < NGT;
       gidx += (long long)gridDim.x*256){
    const float4* s; f16_t* d; long long off;
    if (gidx < NG1){ s = (const float4*)W1; d = w1h; off = gidx; }
    else if (gidx < NG2){ s = (const float4*)W2; d = w2h; off = gidx - NG1; }
    else { s = (const float4*)Wk; d = wkh; off = gidx - NG2; }
    *reinterpret_cast<f16x8*>(d + off*8) = cvt8h(s[off*2], s[off*2+1]);
  }
}

// ---------------------------------------------------------------------------
// k2_fused (ROUND-8 exact): per (expert e, 64-row batch tile):
//   h = x@W1[e]^T + b1 ; LN ; relu -> hr(f16 LDS) ; eo = hr@W2[e]^T + b2 ->
//   global f32 + f16 LDS ; k = eo@Wk^T + bk ; scores[b,hd,e] = q . k
// grid 1024 XCD-swizzled; block 512 = 8 col-waves; LDS 70.1KB -> 2 blocks/CU.
// ---------------------------------------------------------------------------
template<int W16>
__global__ __launch_bounds__(512, 4)
void k2_fused(const float* __restrict__ x, const void* __restrict__ W1v,
              const float* __restrict__ b1, const float* __restrict__ g1,
              const float* __restrict__ bb1, const void* __restrict__ W2v,
              const float* __restrict__ b2, const void* __restrict__ Wkv,
              const float* __restrict__ ipb, const float* __restrict__ q,
              float* __restrict__ eo_out, float* __restrict__ scores)
{
  __shared__ __align__(16) char lds[70144];
  char* bufA = lds;                    // 32KB: x(f16) -> hr(f16) -> eo(f16)
  float* red = (float*)(lds + 32768);  // [64][16] = 4KB
  float* st  = (float*)(lds + 36864);  // [64][2]  = 512B
  char* wpipe = lds + 37376;           // 8 waves x 2 slots x 2KB = 32KB

  const int l = blockIdx.x;
  const int e    = (l & 7) * 32 + (l >> 5);
  const int b0   = ((l >> 3) & 3) * 64;
  const int tid = threadIdx.x;
  const int lane = tid & 63, wid = tid >> 6;
  const int lo16 = lane & 15, hi4 = lane >> 4;
  const int n0 = wid * 32;
  char* wt = wpipe + wid*4096;

  const int pl = (n0 + (lane >> 2))*256 + (lane & 3)*8;
  const f16_t* src1 = nullptr; const f16_t* src2 = nullptr; const f16_t* srcK = nullptr;
  if (W16){
    src1 = (const f16_t*)W1v + e*65536 + pl;
    src2 = (const f16_t*)W2v + e*65536 + pl;
    srcK = (const f16_t*)Wkv + pl;
    issue_tile(src1, 0, wt, lane);       // G1 prefetch hides under x-stage
    issue_tile(src1, 1, wt, lane);
  }

  stage_f16<512>(x + b0*256, bufA, 64, tid);
  __syncthreads();

  f32x4 acc[4][2];
  #pragma unroll
  for (int mb=0;mb<4;++mb){
    #pragma unroll
    for (int nb=0;nb<2;++nb) acc[mb][nb] = (f32x4)0.0f;
  }

  if (W16) gemm_pipe(acc, bufA, src1, wt, lane, lo16, hi4);
  else     gemm_w32(acc, bufA, (const float*)W1v + e*65536, n0, lo16, hi4);

  if (W16){                              // G2 prefetch hides under LN phase
    issue_tile(src2, 0, wt, lane);
    issue_tile(src2, 1, wt, lane);
  }

  float b1v[2], g1v[2], bbv[2];
  #pragma unroll
  for (int nb=0;nb<2;++nb){
    int c = n0 + nb*16 + lo16;
    b1v[nb] = b1[e*256 + c];
    g1v[nb] = g1[e*256 + c];
    bbv[nb] = bb1[e*256 + c];
  }
  #pragma unroll
  for (int mb=0;mb<4;++mb){
    #pragma unroll
    for (int nb=0;nb<2;++nb){
      #pragma unroll
      for (int r=0;r<4;++r) acc[mb][nb][r] += b1v[nb];
    }
  }

  // LN stats: per-row sum/sumsq across the 8 column-waves
  #pragma unroll
  for (int mb=0;mb<4;++mb){
    #pragma unroll
    for (int r=0;r<4;++r){
      float s=0.f, ss=0.f;
      #pragma unroll
      for (int nb=0;nb<2;++nb){ float v = acc[mb][nb][r]; s += v; ss += v*v; }
      #pragma unroll
      for (int m=1;m<16;m<<=1){ s += __shfl_xor(s, m, 64); ss += __shfl_xor(ss, m, 64); }
      if (lo16 == 0){
        int row = mb*16 + hi4*4 + r;
        red[row*16 + wid]     = s;
        red[row*16 + 8 + wid] = ss;
      }
    }
  }
  __syncthreads();   // also: all waves done reading x from bufA
  if (tid < 64){
    float s  = 0.f, ss = 0.f;
    #pragma unroll
    for (int i=0;i<8;++i){ s += red[tid*16 + i]; ss += red[tid*16 + 8 + i]; }
    float mu = s * (1.f/256.f);
    float var = ss * (1.f/256.f) - mu*mu;
    st[tid*2]   = mu;
    st[tid*2+1] = rsqrtf(var + 1e-5f);
  }
  __syncthreads();

  // LN + relu -> hr (f16) back into bufA
  #pragma unroll
  for (int mb=0;mb<4;++mb){
    #pragma unroll
    for (int r=0;r<4;++r){
      int row = mb*16 + hi4*4 + r;
      float mu = st[row*2], rs = st[row*2+1];
      #pragma unroll
      for (int nb=0;nb<2;++nb){
        int c = n0 + nb*16 + lo16;
        float v = (acc[mb][nb][r] - mu) * rs * g1v[nb] + bbv[nb];
        v = fmaxf(v, 0.f);
        int off = row*512 + (((c>>3) ^ (row&7))<<4) + (c&7)*2;
        *reinterpret_cast<f16_t*>(bufA + off) = (f16_t)v;
      }
    }
  }
  __syncthreads();

  // GEMM2: eo = hr @ W2[e]^T + b2
  #pragma unroll
  for (int mb=0;mb<4;++mb){
    #pragma unroll
    for (int nb=0;nb<2;++nb) acc[mb][nb] = (f32x4)0.0f;
  }
  if (W16) gemm_pipe(acc, bufA, src2, wt, lane, lo16, hi4);
  else     gemm_w32(acc, bufA, (const float*)W2v + e*65536, n0, lo16, hi4);

  float b2v[2];
  #pragma unroll
  for (int nb=0;nb<2;++nb) b2v[nb] = b2[e*256 + n0 + nb*16 + lo16];

  __syncthreads();  // all waves done reading hr before eo overwrites bufA

  if (W16){                              // G3 prefetch hides under eo stores
    issue_tile(srcK, 0, wt, lane);
    issue_tile(srcK, 1, wt, lane);
  }

  #pragma unroll
  for (int mb=0;mb<4;++mb){
    #pragma unroll
    for (int r=0;r<4;++r){
      int row = mb*16 + hi4*4 + r;
      int b = b0 + row;
      #pragma unroll
      for (int nb=0;nb<2;++nb){
        int c = n0 + nb*16 + lo16;
        float v = acc[mb][nb][r] + b2v[nb];
        eo_out[(b*256 + e)*256 + c] = v;
        int off = row*512 + (((c>>3) ^ (row&7))<<4) + (c&7)*2;
        *reinterpret_cast<f16_t*>(bufA + off) = (f16_t)v;
      }
    }
  }
  __syncthreads();

  // GEMM3: k = eo @ Wk^T + bk ; scores = q . k
  #pragma unroll
  for (int mb=0;mb<4;++mb){
    #pragma unroll
    for (int nb=0;nb<2;++nb) acc[mb][nb] = (f32x4)0.0f;
  }
  if (W16) gemm_pipe(acc, bufA, srcK, wt, lane, lo16, hi4);
  else     gemm_w32(acc, bufA, (const float*)Wkv, n0, lo16, hi4);

  float bkv[2];
  #pragma unroll
  for (int nb=0;nb<2;++nb) bkv[nb] = ipb[256 + n0 + nb*16 + lo16];

  #pragma unroll
  for (int mb=0;mb<4;++mb){
    #pragma unroll
    for (int r=0;r<4;++r){
      int row = mb*16 + hi4*4 + r;
      int b = b0 + row;
      float p = 0.f;
      #pragma unroll
      for (int nb=0;nb<2;++nb){
        int c = n0 + nb*16 + lo16;
        p += q[b*256 + c] * (acc[mb][nb][r] + bkv[nb]);
      }
      #pragma unroll
      for (int m=1;m<16;m<<=1) p += __shfl_xor(p, m, 64);
      if (lo16 == 0) red[row*16 + wid] = p;   // partial over this wave's 32 cols
    }
  }
  __syncthreads();
  if (tid < 256){
    int row = tid >> 2, hd = tid & 3;
    float sc = red[row*16 + hd*2] + red[row*16 + hd*2 + 1];
    scores[((b0 + row)*4 + hd)*256 + e] = sc;
  }
}

// ---------------------------------------------------------------------------
// k_mini: out = (A @ W^T + bias) * scale, 256x256x256, f16. (q-projection)
// ---------------------------------------------------------------------------
__global__ __launch_bounds__(512, 4)
void k_mini(const float* __restrict__ A, const float* __restrict__ W,
            const float* __restrict__ bias, float scale,
            float* __restrict__ out)
{
  __shared__ __align__(16) char lds[16384];
  char* bufA = lds;                    // 16KB: A rows (f16)

  const int b0 = blockIdx.x * 32;
  const int tid = threadIdx.x;
  const int lane = tid & 63, wid = tid >> 6;
  const int lo16 = lane & 15, hi4 = lane >> 4;
  const int n0 = wid * 32;

  stage_f16<512>(A + b0*256, bufA, 32, tid);
  __syncthreads();

  f32x4 acc[2][2];
  #pragma unroll
  for (int mb=0;mb<2;++mb){
    #pragma unroll
    for (int nb=0;nb<2;++nb) acc[mb][nb] = (f32x4)0.0f;
  }
  #pragma unroll
  for (int kb = 0; kb < 8; ++kb){
    f16x8 bf[2];
    #pragma unroll
    for (int nb = 0; nb < 2; ++nb){
      const float4* p = reinterpret_cast<const float4*>(W + ((n0 + nb*16 + lo16)<<8) + kb*32 + hi4*8);
      bf[nb] = cvt8h(p[0], p[1]);
    }
    #pragma unroll
    for (int mb = 0; mb < 2; ++mb){
      f16x8 af = ldsA(bufA, mb*16 + lo16, kb*4 + hi4);
      acc[mb][0] = MFMA16(af, bf[0], acc[mb][0]);
      acc[mb][1] = MFMA16(af, bf[1], acc[mb][1]);
    }
  }

  float bv[2];
  #pragma unroll
  for (int nb=0;nb<2;++nb) bv[nb] = bias[n0 + nb*16 + lo16];

  #pragma unroll
  for (int mb=0;mb<2;++mb){
    #pragma unroll
    for (int r=0;r<4;++r){
      int row = mb*16 + hi4*4 + r;
      #pragma unroll
      for (int nb=0;nb<2;++nb){
        int c = n0 + nb*16 + lo16;
        out[(b0 + row)*256 + c] = (acc[mb][nb][r] + bv[nb]) * scale;
      }
    }
  }
}

// ---------------------------------------------------------------------------
__global__ __launch_bounds__(256)
void k3_softmax(const float* __restrict__ scores, float* __restrict__ wts)
{
  const int b = blockIdx.x, t = threadIdx.x;
  const int wid = t >> 6, lane = t & 63;
  __shared__ float r4[4];
  float sc[4];
  #pragma unroll
  for (int n=0;n<4;++n) sc[n] = scores[(b*4 + n)*256 + t];
  float wsum = 0.f;
  for (int n=0;n<4;++n){
    float m = sc[n];
    #pragma unroll
    for (int k=1;k<64;k<<=1) m = fmaxf(m, __shfl_xor(m, k, 64));
    if (lane == 0) r4[wid] = m;
    __syncthreads();
    m = fmaxf(fmaxf(r4[0], r4[1]), fmaxf(r4[2], r4[3]));
    __syncthreads();
    float ex = __expf(sc[n] - m);
    float s = ex;
    #pragma unroll
    for (int k=1;k<64;k<<=1) s += __shfl_xor(s, k, 64);
    if (lane == 0) r4[wid] = s;
    __syncthreads();
    s = r4[0] + r4[1] + r4[2] + r4[3];
    __syncthreads();
    wsum += ex / s;
  }
  wts[b*256 + t] = wsum * 0.25f;
}

// ---------------------------------------------------------------------------
// kB: fused k4a + final projection + LN + relu (r15-verified). Per block b:
//   cmb[k] = sum_e eo[b,e,k] * wts_flat[e*256+k]   (reference's literal einsum)
//   y[h]   = sum_k cmb[k] * cw[h,k] + cb[h]
//   out[b,h] = relu((y - mu)*rsqrt(var+eps)*cg + cbt)
// ---------------------------------------------------------------------------
__global__ __launch_bounds__(1024)
void kB_out(const float* __restrict__ eo, const float* __restrict__ wts,
            const float* __restrict__ cw, const float* __restrict__ cb,
            const float* __restrict__ cg, const float* __restrict__ cbt,
            float* __restrict__ out)
{
  __shared__ float part[1024];
  __shared__ float cmb_l[256];
  __shared__ float vl[256];
  __shared__ float st2[2];
  const int b = blockIdx.x, t = threadIdx.x;
  const int c = t >> 8, h = t & 255;

  // phase 1: combined (4-way e-split, coalesced over h)
  {
    const float* p = eo + b*65536 + h;
    float s = 0.f;
    #pragma unroll 8
    for (int i = 0; i < 64; ++i){
      int e2 = c*64 + i;
      s += p[e2*256] * wts[e2*256 + h];
    }
    part[t] = s;
  }
  __syncthreads();
  if (t < 256) cmb_l[t] = part[t] + part[t+256] + part[t+512] + part[t+768];
  __syncthreads();

  // phase 2: y[h] partial over k in [c*64, c*64+64)
  {
    const float* cwr = cw + h*256 + c*64;
    float y = 0.f;
    #pragma unroll 8
    for (int k = 0; k < 64; ++k) y += cmb_l[c*64 + k] * cwr[k];
    part[t] = y;
  }
  __syncthreads();
  if (t < 256) vl[t] = part[t] + part[t+256] + part[t+512] + part[t+768] + cb[t];
  __syncthreads();

  // LN stats over the 256 values (one wave)
  if (t < 64){
    float s = 0.f, ss = 0.f;
    #pragma unroll
    for (int i = 0; i < 4; ++i){
      float v = vl[t*4 + i];
      s += v; ss += v*v;
    }
    #pragma unroll
    for (int m=1;m<64;m<<=1){ s += __shfl_xor(s, m, 64); ss += __shfl_xor(ss, m, 64); }
    if (t == 0){
      float mu = s * (1.f/256.f);
      float var = ss * (1.f/256.f) - mu*mu;
      st2[0] = mu;
      st2[1] = rsqrtf(var + 1e-5f);
    }
  }
  __syncthreads();

  if (t < 256){
    float v = (vl[t] - st2[0]) * st2[1] * cg[t] + cbt[t];
    out[b*256 + t] = fmaxf(v, 0.f);
  }
}

extern "C" void kernel_launch(void* const* d_in, const int* in_sizes, int n_in,
                              void* d_out, int out_size, void* d_ws, size_t ws_size,
                              hipStream_t stream)
{
  const float* x    = (const float*)d_in[0];
  const float* te   = (const float*)d_in[1];
  const float* W1   = (const float*)d_in[2];
  const float* b1   = (const float*)d_in[3];
  const float* g1   = (const float*)d_in[4];
  const float* bb1  = (const float*)d_in[5];
  const float* W2   = (const float*)d_in[6];
  const float* b2   = (const float*)d_in[7];
  const float* ipw  = (const float*)d_in[8];
  const float* ipb  = (const float*)d_in[9];
  const float* cw   = (const float*)d_in[10];
  const float* cb   = (const float*)d_in[11];
  const float* cg   = (const float*)d_in[12];
  const float* cbt  = (const float*)d_in[13];

  float* out    = (float*)d_out;        // (256,256)
  float* wts    = out + 65536;          // (256,1,256)
  float* eo     = out + 131072;         // (256,256,256)

  // ws layout: [w1h 32MB | w2h 32MB | wkh 128KB] | q 256KB | scores 1MB
  const size_t F16_BYTES = 2ull*(16777216ull*2 + 65536);           // 67,239,936
  const size_t NEED = F16_BYTES + 4ull*65536 + 4ull*262144;        // 68,550,656
  const bool f16w = ws_size >= NEED;

  f16_t* w1h = (f16_t*)d_ws;
  f16_t* w2h = w1h + 16777216;
  f16_t* wkh = w2h + 16777216;
  float* fbase = f16w ? (float*)((char*)d_ws + F16_BYTES) : (float*)d_ws;
  float* q      = fbase;                // 65536 f32
  float* scores = q + 65536;            // 262144 f32 (B,4,E)

  // q = (te @ Wq^T + bq) / 8
  k_mini<<<8, 512, 0, stream>>>(te, ipw, ipb, 0.125f, q);

  if (f16w){
    k0_cvt<<<2048, 256, 0, stream>>>(W1, W2, ipw + 65536, w1h, w2h, wkh);
    k2_fused<1><<<1024, 512, 0, stream>>>(x, w1h, b1, g1, bb1, w2h, b2,
                                          wkh, ipb, q, eo, scores);
  } else {
    k2_fused<0><<<1024, 512, 0, stream>>>(x, W1, b1, g1, bb1, W2, b2,
                                          ipw + 65536, ipb, q, eo, scores);
  }

  // softmax over experts, mean over heads -> weights (out)
  k3_softmax<<<256, 256, 0, stream>>>(scores, wts);
  // combined + final projection + LN + relu, fused
  kB_out<<<256, 1024, 0, stream>>>(eo, wts, cw, cb, cg, cbt, out);
}